// Round 4
// baseline (3282.146 us; speedup 1.0000x reference)
//
#include <hip/hip_runtime.h>
#include <math.h>

#define T_LEN 4096
#define D_DIM 512
#define F_DIM 8192
#define NCHUNK 64
#define CLEN 64

// ---------------- helpers ----------------
__device__ inline float wave_sum(float v) {
#pragma unroll
  for (int o = 32; o; o >>= 1) v += __shfl_xor(v, o);
  return v;
}

// start[] may arrive as 1-byte bools or int32 {0,1}. If int32, bytes at
// offset %4 != 0 in the first 4096 bytes are all zero; if bytes, ~60 are 1.
__global__ void detect_start(const unsigned char* __restrict__ s8, int* __restrict__ mode) {
  __shared__ int found;
  if (threadIdx.x == 0) found = 0;
  __syncthreads();
  for (int i = threadIdx.x; i < 4096; i += 256)
    if ((i & 3) && s8[i]) found = 1;  // benign race, same value
  __syncthreads();
  if (threadIdx.x == 0) mode[0] = found;  // 1 = byte layout, 0 = int32 layout
}

__device__ inline int read_start(const unsigned char* s8, const int* s32, int mode, int t) {
  return mode ? (int)s8[t] : s32[t];
}

// ---------------- fp32 VALU GEMM: C[m][coff+n] = sum_k A[m][k] * B[n][k] ----------------
// 64x64 tile, BK=32, 256 threads, 4x4 acc/thread. M,N multiples of 64; K of 32.
__global__ __launch_bounds__(256) void gemm_nt(const float* __restrict__ A,
                                               const float* __restrict__ B,
                                               float* __restrict__ C, int M, int N, int K,
                                               int ldc, int coff) {
  __shared__ float sA[32][64];  // [k][row] (transposed on store)
  __shared__ float sB[32][64];
  const int tid = threadIdx.x;
  const int m0 = blockIdx.x * 64;
  const int n0 = blockIdx.y * 64;
  const int tx = tid & 15;
  const int ty = tid >> 4;
  float acc[4][4];
#pragma unroll
  for (int i = 0; i < 4; ++i)
#pragma unroll
    for (int j = 0; j < 4; ++j) acc[i][j] = 0.f;

  for (int k0 = 0; k0 < K; k0 += 32) {
#pragma unroll
    for (int s = 0; s < 2; ++s) {
      int idx = tid + 256 * s;        // 0..511 -> 64 rows x 8 float4
      int r = idx >> 3;
      int kc = (idx & 7) << 2;
      float4 av = *(const float4*)(A + (size_t)(m0 + r) * K + k0 + kc);
      sA[kc + 0][r] = av.x; sA[kc + 1][r] = av.y;
      sA[kc + 2][r] = av.z; sA[kc + 3][r] = av.w;
      float4 bv = *(const float4*)(B + (size_t)(n0 + r) * K + k0 + kc);
      sB[kc + 0][r] = bv.x; sB[kc + 1][r] = bv.y;
      sB[kc + 2][r] = bv.z; sB[kc + 3][r] = bv.w;
    }
    __syncthreads();
#pragma unroll
    for (int kk = 0; kk < 32; ++kk) {
      float4 a4 = *(const float4*)&sA[kk][ty << 2];
      float4 b4 = *(const float4*)&sB[kk][tx << 2];
      float am[4] = {a4.x, a4.y, a4.z, a4.w};
      float bn[4] = {b4.x, b4.y, b4.z, b4.w};
#pragma unroll
      for (int i = 0; i < 4; ++i)
#pragma unroll
        for (int j = 0; j < 4; ++j) acc[i][j] = fmaf(am[i], bn[j], acc[i][j]);
    }
    __syncthreads();
  }
#pragma unroll
  for (int i = 0; i < 4; ++i) {
    int m = m0 + (ty << 2) + i;
#pragma unroll
    for (int j = 0; j < 4; ++j) {
      int n = n0 + (tx << 2) + j;
      C[(size_t)m * ldc + coff + n] = acc[i][j];
    }
  }
}

// ---------------- p/q prep: p=|tr|, q=|ct|/(1e-8+Sp*Sq) ----------------
__global__ void prep_pq(const float* __restrict__ trct, float* __restrict__ p,
                        float* __restrict__ q) {
  int t = blockIdx.x;
  int lane = threadIdx.x;  // 64
  float tr = trct[t * 128 + lane];
  float ct = trct[t * 128 + 64 + lane];
  float ap = fabsf(tr), aq = fabsf(ct);
  float Sp = wave_sum(ap);
  float Sq = wave_sum(aq);
  float denom = 1e-8f + Sp * Sq;
  p[t * 64 + lane] = ap;
  q[t * 64 + lane] = aq / denom;
}

// ---------------- scan phase 1: per-chunk affine summary (A,B) ----------------
__global__ void scan_phase1(const float* __restrict__ p, const float* __restrict__ q,
                            const unsigned char* __restrict__ st8, const int* __restrict__ st32,
                            const int* __restrict__ modep, const float* __restrict__ a,
                            const float* __restrict__ b, float4* __restrict__ chunkbuf) {
  int chunk = blockIdx.x, r = blockIdx.y, c = threadIdx.x;
  int mode = modep[0];
  float rho = expf(-fabsf(a[r]));
  float bb = b[c];
  float er = rho * cosf(bb), ei = rho * sinf(bb);
  float Ar = 1.f, Ai = 0.f, Br = 0.f, Bi = 0.f;
  int t0 = chunk * CLEN;
  for (int i = 0; i < CLEN; ++i) {
    int t = t0 + i;
    float qt = q[t * 64 + c];
    float pt = p[t * 64 + r];
    int st = read_start(st8, st32, mode, t);
    float pre = pt * qt;
    float cer = st ? 0.f : er;
    float cei = st ? 0.f : ei;
    float nAr = cer * Ar - cei * Ai;
    Ai = cer * Ai + cei * Ar;
    Ar = nAr;
    float nBr = cer * Br - cei * Bi + pre;
    Bi = cer * Bi + cei * Br;
    Br = nBr;
  }
  chunkbuf[((size_t)chunk * 64 + r) * 64 + c] = make_float4(Ar, Ai, Br, Bi);
}

// ---------------- scan phase 2: sequential chunk combine -> per-chunk init states ----------------
__global__ void scan_phase2(const float4* __restrict__ chunkbuf, const float* __restrict__ state,
                            float2* __restrict__ s0buf) {
  int r = blockIdx.x, c = threadIdx.x;
  float Sr = state[r * 64 + c], Si = 0.f;
  for (int k = 0; k < NCHUNK; ++k) {
    s0buf[((size_t)k * 64 + r) * 64 + c] = make_float2(Sr, Si);
    float4 ab = chunkbuf[((size_t)k * 64 + r) * 64 + c];
    float nSr = ab.x * Sr - ab.y * Si + ab.z;
    Si = ab.x * Si + ab.y * Sr + ab.w;
    Sr = nSr;
  }
}

// ---------------- scan phase 3: replay chunks [c0, c0+nch), emit log-polar features (fp32) ----
__global__ void scan_phase3(const float* __restrict__ p, const float* __restrict__ q,
                            const unsigned char* __restrict__ st8, const int* __restrict__ st32,
                            const int* __restrict__ modep, const float* __restrict__ a,
                            const float* __restrict__ b, const float2* __restrict__ s0buf,
                            float* __restrict__ scaled, int c0) {
  int chunk = c0 + blockIdx.x, r = blockIdx.y, c = threadIdx.x;
  int mode = modep[0];
  float rho = expf(-fabsf(a[r]));
  float bb = b[c];
  float er = rho * cosf(bb), ei = rho * sinf(bb);
  float2 s0 = s0buf[((size_t)chunk * 64 + r) * 64 + c];
  float Sr = s0.x, Si = s0.y;
  int t0 = chunk * CLEN;
  int tl0 = (chunk - c0) * CLEN;  // local row within the segment buffer
  for (int i = 0; i < CLEN; ++i) {
    int t = t0 + i;
    float qt = q[t * 64 + c];
    float pt = p[t * 64 + r];
    int st = read_start(st8, st32, mode, t);
    float pre = pt * qt;
    float cer = st ? 0.f : er;
    float cei = st ? 0.f : ei;
    float nSr = cer * Sr - cei * Si + pre;
    Si = cer * Si + cei * Sr;
    Sr = nSr;
    float m2 = Sr * Sr + Si * Si;
    float m = sqrtf(m2);
    float mag = log1pf(m);
    float sc = mag / fmaxf(m, 1e-30f);
    size_t base = (size_t)(tl0 + i) * F_DIM + r * 64 + c;
    scaled[base] = sc * Si;         // mag*sin(angle)
    scaled[base + 4096] = sc * Sr;  // mag*cos(angle)
  }
}

// ---------------- LayerNorm + LeakyReLU ----------------
// zout: layer-internal z (post-act). xdst = xsrc + z (residual). finout: final z.
__global__ void ln_act(const float* __restrict__ y, const float* __restrict__ bias,
                       const float* __restrict__ gam, const float* __restrict__ bet,
                       float* __restrict__ zout, const float* __restrict__ xsrc,
                       float* __restrict__ xdst, float* __restrict__ finout) {
  __shared__ float red[8];
  int t = blockIdx.x, tid = threadIdx.x;
  const float* row = y + (size_t)t * D_DIM;
  float v0 = row[tid] + bias[tid];
  float v1 = row[tid + 256] + bias[tid + 256];
  float s = wave_sum(v0 + v1);
  if ((tid & 63) == 0) red[tid >> 6] = s;
  __syncthreads();
  float mean = (red[0] + red[1] + red[2] + red[3]) * (1.f / 512.f);
  float d0 = v0 - mean, d1 = v1 - mean;
  float s2 = wave_sum(d0 * d0 + d1 * d1);
  if ((tid & 63) == 0) red[4 + (tid >> 6)] = s2;
  __syncthreads();
  float var = (red[4] + red[5] + red[6] + red[7]) * (1.f / 512.f);
  float rstd = rsqrtf(var + 1e-5f);
  float z0 = d0 * rstd * gam[tid] + bet[tid];
  float z1 = d1 * rstd * gam[tid + 256] + bet[tid + 256];
  z0 = z0 > 0.f ? z0 : 0.01f * z0;
  z1 = z1 > 0.f ? z1 : 0.01f * z1;
  size_t o = (size_t)t * D_DIM + tid;
  if (zout) { zout[o] = z0; zout[o + 256] = z1; }
  if (xdst) { xdst[o] = xsrc[o] + z0; xdst[o + 256] = xsrc[o + 256] + z1; }
  if (finout) { finout[o] = z0; finout[o + 256] = z1; }
}

// ---------------- canary: stage liveness -> readable absmax code ----------------
__global__ void canary(const float* __restrict__ trct, const float* __restrict__ scaled,
                       const float* __restrict__ ybuf, const float* __restrict__ z0f,
                       float* __restrict__ out) {
  __shared__ float tot[5];
  int tid = threadIdx.x;
  if (tid < 5) tot[tid] = 0.f;
  __syncthreads();
  float s[5] = {0.f, 0.f, 0.f, 0.f, 0.f};
  for (int i = tid; i < 4096; i += 256) {
    s[0] += fabsf(trct[i]);
    s[1] += fabsf(scaled[i]);
    s[2] += fabsf(ybuf[i]);
    s[3] += fabsf(z0f[i]);
    s[4] += fabsf(out[i]);
  }
#pragma unroll
  for (int k = 0; k < 5; ++k) {
    float w = wave_sum(s[k]);
    if ((tid & 63) == 0) atomicAdd(&tot[k], w);
  }
  __syncthreads();
  if (tid == 0) {
    float code = 0.f;
    if (tot[0] < 1e-6f) code = 1e6f;        // trct dead (input GEMM / x path)
    else if (tot[1] < 1e-12f) code = 2e6f;  // scaled dead (scan)
    else if (tot[2] < 1e-12f) code = 3e6f;  // ybuf dead (big GEMM)
    else if (tot[3] < 1e-3f) code = 4e6f;   // z0 dead (LN)
    else if (tot[4] < 1e-3f) code = 5e6f;   // out never written
    if (code > 0.f) out[0] = code;
  }
}

__global__ void err_signal(float* __restrict__ out, float code) {
  if (threadIdx.x == 0) out[0] = code;
}

// ---------------- host launch ----------------
extern "C" void kernel_launch(void* const* d_in, const int* in_sizes, int n_in, void* d_out,
                              int out_size, void* d_ws, size_t ws_size, hipStream_t stream) {
  const float* x_in = (const float*)d_in[0];
  const float* state = (const float*)d_in[1];
  const unsigned char* start8 = (const unsigned char*)d_in[2];
  const int* start32 = (const int*)d_in[2];
  const float* Wtr = (const float*)d_in[3];
  const float* Wc = (const float*)d_in[4];
  const float* a_in = (const float*)d_in[5];
  const float* b_in = (const float*)d_in[6];
  const float* W0 = (const float*)d_in[7];
  const float* b0 = (const float*)d_in[8];
  const float* g0 = (const float*)d_in[9];
  const float* beta0 = (const float*)d_in[10];
  const float* W1 = (const float*)d_in[11];
  const float* b1 = (const float*)d_in[12];
  const float* g1 = (const float*)d_in[13];
  const float* beta1 = (const float*)d_in[14];
  float* out = (float*)d_out;

  char* w = (char*)d_ws;
  auto alloc = [&](size_t bytes) {
    char* ptr = w;
    w += (bytes + 255) & ~(size_t)255;
    return ptr;
  };
  float* x_ws = (float*)alloc(4ull * T_LEN * D_DIM);            // 8 MB
  float* trct = (float*)alloc(4ull * T_LEN * 128);              // 2 MB
  float* pbuf = (float*)alloc(4ull * T_LEN * 64);               // 1 MB
  float* qbuf = (float*)alloc(4ull * T_LEN * 64);               // 1 MB
  float4* chunkbuf = (float4*)alloc(16ull * NCHUNK * 64 * 64);  // 4 MB
  float2* s0buf = (float2*)alloc(8ull * NCHUNK * 64 * 64);      // 2 MB
  float* ybuf = (float*)alloc(4ull * T_LEN * D_DIM);            // 8 MB
  float* z0f = (float*)alloc(4ull * T_LEN * D_DIM);             // 8 MB
  int* modep = (int*)alloc(256);
  size_t base_used = (size_t)(w - (char*)d_ws);

  if (n_in != 15) {
    err_signal<<<1, 64, 0, stream>>>(out, 9e6f + 1000.f * n_in);
    return;
  }
  // segment count for the (T x 8192) feature buffer: halves if ws allows, else quarters
  int nseg;
  if (ws_size >= base_used + 4ull * 2048 * F_DIM) nseg = 2;
  else if (ws_size >= base_used + 4ull * 1024 * F_DIM) nseg = 4;
  else {
    err_signal<<<1, 64, 0, stream>>>(out, 9e6f);
    return;
  }
  const int seg_rows = T_LEN / nseg;     // 2048 or 1024
  const int seg_chunks = NCHUNK / nseg;  // 32 or 16
  float* scaled = (float*)alloc(4ull * seg_rows * F_DIM);

  detect_start<<<1, 256, 0, stream>>>(start8, modep);

  for (int l = 0; l < 3; ++l) {
    const float* Wtr_l = Wtr + (size_t)l * 64 * D_DIM;
    const float* Wc_l = Wc + (size_t)l * 64 * D_DIM;
    const float* a_l = a_in + l * 64;
    const float* b_l = b_in + l * 64;
    const float* W0_l = W0 + (size_t)l * D_DIM * F_DIM;
    const float* W1_l = W1 + (size_t)l * D_DIM * D_DIM;
    const float* state_l = state + (size_t)l * 64 * 64;
    const float* xcur = (l == 0) ? x_in : x_ws;

    // tr = x @ Wtr^T -> trct[:, 0:64];  ct = x @ Wc^T -> trct[:, 64:128]
    gemm_nt<<<dim3(T_LEN / 64, 1), 256, 0, stream>>>(xcur, Wtr_l, trct, T_LEN, 64, D_DIM, 128, 0);
    gemm_nt<<<dim3(T_LEN / 64, 1), 256, 0, stream>>>(xcur, Wc_l, trct, T_LEN, 64, D_DIM, 128, 64);
    prep_pq<<<T_LEN, 64, 0, stream>>>(trct, pbuf, qbuf);
    scan_phase1<<<dim3(NCHUNK, 64), 64, 0, stream>>>(pbuf, qbuf, start8, start32, modep, a_l,
                                                     b_l, chunkbuf);
    scan_phase2<<<64, 64, 0, stream>>>(chunkbuf, state_l, s0buf);

    for (int h = 0; h < nseg; ++h) {
      scan_phase3<<<dim3(seg_chunks, 64), 64, 0, stream>>>(pbuf, qbuf, start8, start32, modep,
                                                           a_l, b_l, s0buf, scaled,
                                                           h * seg_chunks);
      // y segment = scaled (seg_rows x 8192) @ W0 (512 x 8192)^T
      gemm_nt<<<dim3(seg_rows / 64, D_DIM / 64), 256, 0, stream>>>(
          scaled, W0_l, ybuf + (size_t)h * seg_rows * D_DIM, seg_rows, D_DIM, F_DIM, D_DIM, 0);
    }
    ln_act<<<T_LEN, 256, 0, stream>>>(ybuf, b0 + l * D_DIM, g0 + l * D_DIM, beta0 + l * D_DIM,
                                      z0f, nullptr, nullptr, nullptr);
    // y2 = z0 (4096x512) @ W1 (512x512)^T
    gemm_nt<<<dim3(T_LEN / 64, D_DIM / 64), 256, 0, stream>>>(z0f, W1_l, ybuf, T_LEN, D_DIM,
                                                              D_DIM, D_DIM, 0);
    ln_act<<<T_LEN, 256, 0, stream>>>(ybuf, b1 + l * D_DIM, g1 + l * D_DIM, beta1 + l * D_DIM,
                                      nullptr, (l < 2) ? xcur : nullptr,
                                      (l < 2) ? x_ws : nullptr, (l == 2) ? out : nullptr);
  }
  canary<<<1, 256, 0, stream>>>(trct, scaled, ybuf, z0f, out);
}

// Round 6
// 902.611 us; speedup vs baseline: 3.6363x; 3.6363x over previous
//
#include <hip/hip_runtime.h>
#include <hip/hip_bf16.h>
#include <math.h>

#define T_LEN 4096
#define D_DIM 512
#define F_DIM 8192
#define NCHUNK 64
#define CLEN 64

typedef short short8 __attribute__((ext_vector_type(8)));
typedef float f32x4 __attribute__((ext_vector_type(4)));
typedef unsigned short u16;

// ---------------- helpers ----------------
__device__ inline float wave_sum(float v) {
#pragma unroll
  for (int o = 32; o; o >>= 1) v += __shfl_xor(v, o);
  return v;
}

__device__ inline u16 f2bf_bits(float v) {
  __hip_bfloat16 h = __float2bfloat16(v);
  return *(u16*)&h;
}

// start[] may arrive as 1-byte bools or int32 {0,1}.
__global__ void detect_start(const unsigned char* __restrict__ s8, int* __restrict__ mode) {
  __shared__ int found;
  if (threadIdx.x == 0) found = 0;
  __syncthreads();
  for (int i = threadIdx.x; i < 4096; i += 256)
    if ((i & 3) && s8[i]) found = 1;  // benign race, same value
  __syncthreads();
  if (threadIdx.x == 0) mode[0] = found;  // 1 = byte layout, 0 = int32 layout
}

__device__ inline int read_start(const unsigned char* s8, const int* s32, int mode, int t) {
  return mode ? (int)s8[t] : s32[t];
}

// ---------------- fp32 -> bf16(bits) convert ----------------
__global__ void f2bf(const float* __restrict__ s, u16* __restrict__ d, int n) {
  int i = blockIdx.x * 256 + threadIdx.x;
  if (i < n) d[i] = f2bf_bits(s[i]);
}

// concat [Wtr_l; Wc_l] -> (128 x 512) bf16
__global__ void k_wcat(const float* __restrict__ wtr, const float* __restrict__ wc,
                       u16* __restrict__ dst) {
  int i = blockIdx.x * 256 + threadIdx.x;  // n = 128*512
  float v = (i < 64 * D_DIM) ? wtr[i] : wc[i - 64 * D_DIM];
  dst[i] = f2bf_bits(v);
}

// ---------------- MFMA GEMM: C[M][N] = A[M][K] @ B[N][K]^T (bf16-bits in, fp32 out) ----------------
// Plain synchronous LDS staging (uint4 load -> uint4 store), m92-style fragments.
template <int BM, int BN, int WR, int WC>
__global__ __launch_bounds__(256) void gemm_bt(const u16* __restrict__ A,
                                               const u16* __restrict__ B,
                                               float* __restrict__ C, int M, int N, int K) {
  constexpr int BK = 32;
  constexpr int MT = BM / (WR * 16);
  constexpr int NT = BN / (WC * 16);
  constexpr int AG = BM / 64;  // staging groups: 256 thr x 8 elems = 64 rows x 32 k
  constexpr int BG = BN / 64;
  __shared__ u16 sA[BM * BK];
  __shared__ u16 sB[BN * BK];
  const int m0 = blockIdx.x * BM;
  const int n0 = blockIdx.y * BN;
  const int tid = threadIdx.x;
  const int wave = tid >> 6;
  const int lane = tid & 63;
  const int wr = wave / WC;
  const int wc = wave % WC;
  const int row_l = tid >> 2;         // 0..63
  const int c8 = (tid & 3) << 3;      // k-offset (elems), 16B granule
  const int frow = lane & 15;         // fragment row: m (or n)
  const int fcol = (lane >> 4) << 3;  // fragment k-offset: quad*8

  f32x4 acc[MT][NT];
#pragma unroll
  for (int i = 0; i < MT; ++i)
#pragma unroll
    for (int j = 0; j < NT; ++j) acc[i][j] = (f32x4){0.f, 0.f, 0.f, 0.f};

  for (int k0 = 0; k0 < K; k0 += BK) {
#pragma unroll
    for (int j = 0; j < AG; ++j) {
      uint4 v = *(const uint4*)(A + (size_t)(m0 + j * 64 + row_l) * K + (k0 + c8));
      *(uint4*)(sA + (j * 64 + row_l) * BK + c8) = v;
    }
#pragma unroll
    for (int j = 0; j < BG; ++j) {
      uint4 v = *(const uint4*)(B + (size_t)(n0 + j * 64 + row_l) * K + (k0 + c8));
      *(uint4*)(sB + (j * 64 + row_l) * BK + c8) = v;
    }
    __syncthreads();
    short8 af[MT], bfr[NT];
#pragma unroll
    for (int i = 0; i < MT; ++i)
      af[i] = *(const short8*)(sA + (wr * MT * 16 + i * 16 + frow) * BK + fcol);
#pragma unroll
    for (int j = 0; j < NT; ++j)
      bfr[j] = *(const short8*)(sB + (wc * NT * 16 + j * 16 + frow) * BK + fcol);
#pragma unroll
    for (int i = 0; i < MT; ++i)
#pragma unroll
      for (int j = 0; j < NT; ++j)
        acc[i][j] = __builtin_amdgcn_mfma_f32_16x16x32_bf16(af[i], bfr[j], acc[i][j], 0, 0, 0);
    __syncthreads();
  }
  // C/D layout: col = lane&15, row = (lane>>4)*4 + reg  (verified m89/m91)
#pragma unroll
  for (int i = 0; i < MT; ++i) {
    const int rbase = m0 + wr * MT * 16 + i * 16 + ((lane >> 4) << 2);
#pragma unroll
    for (int j = 0; j < NT; ++j) {
      const int col = n0 + wc * NT * 16 + j * 16 + (lane & 15);
#pragma unroll
      for (int rg = 0; rg < 4; ++rg) C[(size_t)(rbase + rg) * N + col] = acc[i][j][rg];
    }
  }
}

// ---------------- p/q prep: p=|tr|, q=|ct|/(1e-8+Sp*Sq) ----------------
__global__ void prep_pq(const float* __restrict__ trct, float* __restrict__ p,
                        float* __restrict__ q) {
  int t = blockIdx.x;
  int lane = threadIdx.x;  // 64
  float tr = trct[t * 128 + lane];
  float ct = trct[t * 128 + 64 + lane];
  float ap = fabsf(tr), aq = fabsf(ct);
  float Sp = wave_sum(ap);
  float Sq = wave_sum(aq);
  float denom = 1e-8f + Sp * Sq;
  p[t * 64 + lane] = ap;
  q[t * 64 + lane] = aq / denom;
}

// ---------------- scan phase 1: per-chunk affine summary (A,B) ----------------
__global__ void scan_phase1(const float* __restrict__ p, const float* __restrict__ q,
                            const unsigned char* __restrict__ st8, const int* __restrict__ st32,
                            const int* __restrict__ modep, const float* __restrict__ a,
                            const float* __restrict__ b, float4* __restrict__ chunkbuf) {
  int chunk = blockIdx.x, r = blockIdx.y, c = threadIdx.x;
  int mode = modep[0];
  float rho = expf(-fabsf(a[r]));
  float bb = b[c];
  float er = rho * cosf(bb), ei = rho * sinf(bb);
  float Ar = 1.f, Ai = 0.f, Br = 0.f, Bi = 0.f;
  int t0 = chunk * CLEN;
  for (int i = 0; i < CLEN; ++i) {
    int t = t0 + i;
    float qt = q[t * 64 + c];
    float pt = p[t * 64 + r];
    int st = read_start(st8, st32, mode, t);
    float pre = pt * qt;
    float cer = st ? 0.f : er;
    float cei = st ? 0.f : ei;
    float nAr = cer * Ar - cei * Ai;
    Ai = cer * Ai + cei * Ar;
    Ar = nAr;
    float nBr = cer * Br - cei * Bi + pre;
    Bi = cer * Bi + cei * Br;
    Br = nBr;
  }
  chunkbuf[((size_t)chunk * 64 + r) * 64 + c] = make_float4(Ar, Ai, Br, Bi);
}

// ---------------- scan phase 2: sequential chunk combine ----------------
__global__ void scan_phase2(const float4* __restrict__ chunkbuf, const float* __restrict__ state,
                            float2* __restrict__ s0buf) {
  int r = blockIdx.x, c = threadIdx.x;
  float Sr = state[r * 64 + c], Si = 0.f;
  for (int k = 0; k < NCHUNK; ++k) {
    s0buf[((size_t)k * 64 + r) * 64 + c] = make_float2(Sr, Si);
    float4 ab = chunkbuf[((size_t)k * 64 + r) * 64 + c];
    float nSr = ab.x * Sr - ab.y * Si + ab.z;
    Si = ab.x * Si + ab.y * Sr + ab.w;
    Sr = nSr;
  }
}

// ---------------- scan phase 3: replay chunks [c0, c0+nch), emit log-polar (bf16 bits) ----
__global__ void scan_phase3(const float* __restrict__ p, const float* __restrict__ q,
                            const unsigned char* __restrict__ st8, const int* __restrict__ st32,
                            const int* __restrict__ modep, const float* __restrict__ a,
                            const float* __restrict__ b, const float2* __restrict__ s0buf,
                            u16* __restrict__ scaled, int c0) {
  int chunk = c0 + blockIdx.x, r = blockIdx.y, c = threadIdx.x;
  int mode = modep[0];
  float rho = expf(-fabsf(a[r]));
  float bb = b[c];
  float er = rho * cosf(bb), ei = rho * sinf(bb);
  float2 s0 = s0buf[((size_t)chunk * 64 + r) * 64 + c];
  float Sr = s0.x, Si = s0.y;
  int t0 = chunk * CLEN;
  int tl0 = (chunk - c0) * CLEN;  // local row within the segment buffer
  for (int i = 0; i < CLEN; ++i) {
    int t = t0 + i;
    float qt = q[t * 64 + c];
    float pt = p[t * 64 + r];
    int st = read_start(st8, st32, mode, t);
    float pre = pt * qt;
    float cer = st ? 0.f : er;
    float cei = st ? 0.f : ei;
    float nSr = cer * Sr - cei * Si + pre;
    Si = cer * Si + cei * Sr;
    Sr = nSr;
    float m2 = Sr * Sr + Si * Si;
    float m = sqrtf(m2);
    float mag = log1pf(m);
    float sc = mag / fmaxf(m, 1e-30f);
    size_t base = (size_t)(tl0 + i) * F_DIM + r * 64 + c;
    scaled[base] = f2bf_bits(sc * Si);         // mag*sin(angle)
    scaled[base + 4096] = f2bf_bits(sc * Sr);  // mag*cos(angle)
  }
}

// ---------------- LayerNorm + LeakyReLU ----------------
// zbf: layer-internal z as bf16 (GEMM input). xdst = xsrc + z. finout: final fp32 out.
__global__ void ln_act(const float* __restrict__ y, const float* __restrict__ bias,
                       const float* __restrict__ gam, const float* __restrict__ bet,
                       u16* __restrict__ zbf, const float* __restrict__ xsrc,
                       float* __restrict__ xdst, float* __restrict__ finout) {
  __shared__ float red[8];
  int t = blockIdx.x, tid = threadIdx.x;
  const float* row = y + (size_t)t * D_DIM;
  float v0 = row[tid] + bias[tid];
  float v1 = row[tid + 256] + bias[tid + 256];
  float s = wave_sum(v0 + v1);
  if ((tid & 63) == 0) red[tid >> 6] = s;
  __syncthreads();
  float mean = (red[0] + red[1] + red[2] + red[3]) * (1.f / 512.f);
  float d0 = v0 - mean, d1 = v1 - mean;
  float s2 = wave_sum(d0 * d0 + d1 * d1);
  if ((tid & 63) == 0) red[4 + (tid >> 6)] = s2;
  __syncthreads();
  float var = (red[4] + red[5] + red[6] + red[7]) * (1.f / 512.f);
  float rstd = rsqrtf(var + 1e-5f);
  float z0 = d0 * rstd * gam[tid] + bet[tid];
  float z1 = d1 * rstd * gam[tid + 256] + bet[tid + 256];
  z0 = z0 > 0.f ? z0 : 0.01f * z0;
  z1 = z1 > 0.f ? z1 : 0.01f * z1;
  size_t o = (size_t)t * D_DIM + tid;
  if (zbf) { zbf[o] = f2bf_bits(z0); zbf[o + 256] = f2bf_bits(z1); }
  if (xdst) { xdst[o] = xsrc[o] + z0; xdst[o + 256] = xsrc[o + 256] + z1; }
  if (finout) { finout[o] = z0; finout[o + 256] = z1; }
}

__global__ void err_signal(float* __restrict__ out, float code) {
  if (threadIdx.x == 0) out[0] = code;
}

// ---------------- host launch ----------------
extern "C" void kernel_launch(void* const* d_in, const int* in_sizes, int n_in, void* d_out,
                              int out_size, void* d_ws, size_t ws_size, hipStream_t stream) {
  const float* x_in = (const float*)d_in[0];
  const float* state = (const float*)d_in[1];
  const unsigned char* start8 = (const unsigned char*)d_in[2];
  const int* start32 = (const int*)d_in[2];
  const float* Wtr = (const float*)d_in[3];
  const float* Wc = (const float*)d_in[4];
  const float* a_in = (const float*)d_in[5];
  const float* b_in = (const float*)d_in[6];
  const float* W0 = (const float*)d_in[7];
  const float* b0 = (const float*)d_in[8];
  const float* g0 = (const float*)d_in[9];
  const float* beta0 = (const float*)d_in[10];
  const float* W1 = (const float*)d_in[11];
  const float* b1 = (const float*)d_in[12];
  const float* g1 = (const float*)d_in[13];
  const float* beta1 = (const float*)d_in[14];
  float* out = (float*)d_out;

  char* w = (char*)d_ws;
  auto alloc = [&](size_t bytes) {
    char* ptr = w;
    w += (bytes + 255) & ~(size_t)255;
    return ptr;
  };
  float* x_ws = (float*)alloc(4ull * T_LEN * D_DIM);            // 8 MB
  u16* xbf = (u16*)alloc(2ull * T_LEN * D_DIM);                 // 4 MB
  u16* wcat = (u16*)alloc(2ull * 128 * D_DIM);                  // 128 KB
  u16* w0bf = (u16*)alloc(2ull * D_DIM * F_DIM);                // 8 MB
  u16* w1bf = (u16*)alloc(2ull * D_DIM * D_DIM);                // 512 KB
  float* trct = (float*)alloc(4ull * T_LEN * 128);              // 2 MB
  float* pbuf = (float*)alloc(4ull * T_LEN * 64);               // 1 MB
  float* qbuf = (float*)alloc(4ull * T_LEN * 64);               // 1 MB
  float4* chunkbuf = (float4*)alloc(16ull * NCHUNK * 64 * 64);  // 4 MB
  float2* s0buf = (float2*)alloc(8ull * NCHUNK * 64 * 64);      // 2 MB
  float* ybuf = (float*)alloc(4ull * T_LEN * D_DIM);            // 8 MB
  u16* z0bf = (u16*)alloc(2ull * T_LEN * D_DIM);                // 4 MB
  int* modep = (int*)alloc(256);
  size_t base_used = (size_t)(w - (char*)d_ws);

  if (n_in != 15) {
    err_signal<<<1, 64, 0, stream>>>(out, 9e6f + 1000.f * n_in);
    return;
  }
  // segment count for the (T x 8192) bf16 feature buffer
  int nseg;
  if (ws_size >= base_used + 2ull * T_LEN * F_DIM) nseg = 1;
  else if (ws_size >= base_used + 2ull * 2048 * F_DIM) nseg = 2;
  else if (ws_size >= base_used + 2ull * 1024 * F_DIM) nseg = 4;
  else {
    err_signal<<<1, 64, 0, stream>>>(out, 9e6f);
    return;
  }
  const int seg_rows = T_LEN / nseg;
  const int seg_chunks = NCHUNK / nseg;
  u16* scaled = (u16*)alloc(2ull * seg_rows * F_DIM);

  detect_start<<<1, 256, 0, stream>>>(start8, modep);

  for (int l = 0; l < 3; ++l) {
    const float* Wtr_l = Wtr + (size_t)l * 64 * D_DIM;
    const float* Wc_l = Wc + (size_t)l * 64 * D_DIM;
    const float* a_l = a_in + l * 64;
    const float* b_l = b_in + l * 64;
    const float* W0_l = W0 + (size_t)l * D_DIM * F_DIM;
    const float* W1_l = W1 + (size_t)l * D_DIM * D_DIM;
    const float* state_l = state + (size_t)l * 64 * 64;
    const float* xcur = (l == 0) ? x_in : x_ws;

    f2bf<<<(T_LEN * D_DIM) / 256, 256, 0, stream>>>(xcur, xbf, T_LEN * D_DIM);
    k_wcat<<<(128 * D_DIM) / 256, 256, 0, stream>>>(Wtr_l, Wc_l, wcat);
    f2bf<<<(D_DIM * F_DIM) / 256, 256, 0, stream>>>(W0_l, w0bf, D_DIM * F_DIM);
    f2bf<<<(D_DIM * D_DIM) / 256, 256, 0, stream>>>(W1_l, w1bf, D_DIM * D_DIM);

    // trct (4096 x 128) = xbf (4096x512) @ wcat(128x512)^T
    gemm_bt<64, 64, 2, 2><<<dim3(T_LEN / 64, 2), 256, 0, stream>>>(xbf, wcat, trct, T_LEN, 128,
                                                                   D_DIM);
    prep_pq<<<T_LEN, 64, 0, stream>>>(trct, pbuf, qbuf);
    scan_phase1<<<dim3(NCHUNK, 64), 64, 0, stream>>>(pbuf, qbuf, start8, start32, modep, a_l,
                                                     b_l, chunkbuf);
    scan_phase2<<<64, 64, 0, stream>>>(chunkbuf, state_l, s0buf);

    for (int h = 0; h < nseg; ++h) {
      scan_phase3<<<dim3(seg_chunks, 64), 64, 0, stream>>>(pbuf, qbuf, start8, start32, modep,
                                                           a_l, b_l, s0buf, scaled,
                                                           h * seg_chunks);
      // y segment = scaled (seg_rows x 8192) @ W0 (512 x 8192)^T
      gemm_bt<64, 64, 2, 2><<<dim3(seg_rows / 64, D_DIM / 64), 256, 0, stream>>>(
          scaled, w0bf, ybuf + (size_t)h * seg_rows * D_DIM, seg_rows, D_DIM, F_DIM);
    }
    ln_act<<<T_LEN, 256, 0, stream>>>(ybuf, b0 + l * D_DIM, g0 + l * D_DIM, beta0 + l * D_DIM,
                                      z0bf, nullptr, nullptr, nullptr);
    // y2 = z0 (4096x512) @ W1 (512x512)^T
    gemm_bt<64, 64, 2, 2><<<dim3(T_LEN / 64, D_DIM / 64), 256, 0, stream>>>(z0bf, w1bf, ybuf,
                                                                            T_LEN, D_DIM, D_DIM);
    ln_act<<<T_LEN, 256, 0, stream>>>(ybuf, b1 + l * D_DIM, g1 + l * D_DIM, beta1 + l * D_DIM,
                                      nullptr, (l < 2) ? xcur : nullptr,
                                      (l < 2) ? x_ws : nullptr, (l == 2) ? out : nullptr);
  }
}

// Round 7
// 752.352 us; speedup vs baseline: 4.3625x; 1.1997x over previous
//
#include <hip/hip_runtime.h>
#include <hip/hip_bf16.h>
#include <math.h>

#define T_LEN 4096
#define D_DIM 512
#define F_DIM 8192
#define NCHUNK 64
#define CLEN 64

typedef short short8 __attribute__((ext_vector_type(8)));
typedef float f32x4 __attribute__((ext_vector_type(4)));
typedef unsigned short u16;

// ---------------- helpers ----------------
__device__ inline float wave_sum(float v) {
#pragma unroll
  for (int o = 32; o; o >>= 1) v += __shfl_xor(v, o);
  return v;
}

__device__ inline u16 f2bf_bits(float v) {
  __hip_bfloat16 h = __float2bfloat16(v);
  return *(u16*)&h;
}

__device__ inline void gl_lds16(const void* g, void* l) {
  __builtin_amdgcn_global_load_lds((const __attribute__((address_space(1))) void*)g,
                                   (__attribute__((address_space(3))) void*)l, 16, 0, 0);
}

// start[] may arrive as 1-byte bools or int32 {0,1}.
__global__ void detect_start(const unsigned char* __restrict__ s8, int* __restrict__ mode) {
  __shared__ int found;
  if (threadIdx.x == 0) found = 0;
  __syncthreads();
  for (int i = threadIdx.x; i < 4096; i += 256)
    if ((i & 3) && s8[i]) found = 1;  // benign race, same value
  __syncthreads();
  if (threadIdx.x == 0) mode[0] = found;  // 1 = byte layout, 0 = int32 layout
}

__device__ inline int read_start(const unsigned char* s8, const int* s32, int mode, int t) {
  return mode ? (int)s8[t] : s32[t];
}

// ---------------- fp32 -> bf16(bits) convert ----------------
__global__ void f2bf(const float* __restrict__ s, u16* __restrict__ d, int n) {
  int i = blockIdx.x * 256 + threadIdx.x;
  if (i < n) d[i] = f2bf_bits(s[i]);
}

// concat [Wtr_l; Wc_l] -> (128 x 512) bf16
__global__ void k_wcat(const float* __restrict__ wtr, const float* __restrict__ wc,
                       u16* __restrict__ dst) {
  int i = blockIdx.x * 256 + threadIdx.x;  // n = 128*512
  float v = (i < 64 * D_DIM) ? wtr[i] : wc[i - 64 * D_DIM];
  dst[i] = f2bf_bits(v);
}

// ---------------- small MFMA GEMM (64x64 tile, sync staging) — used for trct ----------------
template <int BM, int BN, int WR, int WC>
__global__ __launch_bounds__(256) void gemm_bt(const u16* __restrict__ A,
                                               const u16* __restrict__ B,
                                               float* __restrict__ C, int M, int N, int K) {
  constexpr int BK = 32;
  constexpr int MT = BM / (WR * 16);
  constexpr int NT = BN / (WC * 16);
  constexpr int AG = BM / 64;
  constexpr int BG = BN / 64;
  __shared__ u16 sA[BM * BK];
  __shared__ u16 sB[BN * BK];
  const int m0 = blockIdx.x * BM;
  const int n0 = blockIdx.y * BN;
  const int tid = threadIdx.x;
  const int wave = tid >> 6;
  const int lane = tid & 63;
  const int wr = wave / WC;
  const int wc = wave % WC;
  const int row_l = tid >> 2;
  const int c8 = (tid & 3) << 3;
  const int frow = lane & 15;
  const int fcol = (lane >> 4) << 3;

  f32x4 acc[MT][NT];
#pragma unroll
  for (int i = 0; i < MT; ++i)
#pragma unroll
    for (int j = 0; j < NT; ++j) acc[i][j] = (f32x4){0.f, 0.f, 0.f, 0.f};

  for (int k0 = 0; k0 < K; k0 += BK) {
#pragma unroll
    for (int j = 0; j < AG; ++j) {
      uint4 v = *(const uint4*)(A + (size_t)(m0 + j * 64 + row_l) * K + (k0 + c8));
      *(uint4*)(sA + (j * 64 + row_l) * BK + c8) = v;
    }
#pragma unroll
    for (int j = 0; j < BG; ++j) {
      uint4 v = *(const uint4*)(B + (size_t)(n0 + j * 64 + row_l) * K + (k0 + c8));
      *(uint4*)(sB + (j * 64 + row_l) * BK + c8) = v;
    }
    __syncthreads();
    short8 af[MT], bfr[NT];
#pragma unroll
    for (int i = 0; i < MT; ++i)
      af[i] = *(const short8*)(sA + (wr * MT * 16 + i * 16 + frow) * BK + fcol);
#pragma unroll
    for (int j = 0; j < NT; ++j)
      bfr[j] = *(const short8*)(sB + (wc * NT * 16 + j * 16 + frow) * BK + fcol);
#pragma unroll
    for (int i = 0; i < MT; ++i)
#pragma unroll
      for (int j = 0; j < NT; ++j)
        acc[i][j] = __builtin_amdgcn_mfma_f32_16x16x32_bf16(af[i], bfr[j], acc[i][j], 0, 0, 0);
    __syncthreads();
  }
#pragma unroll
  for (int i = 0; i < MT; ++i) {
    const int rbase = m0 + wr * MT * 16 + i * 16 + ((lane >> 4) << 2);
#pragma unroll
    for (int j = 0; j < NT; ++j) {
      const int col = n0 + wc * NT * 16 + j * 16 + (lane & 15);
#pragma unroll
      for (int rg = 0; rg < 4; ++rg) C[(size_t)(rbase + rg) * N + col] = acc[i][j][rg];
    }
  }
}

// ---------------- m97-style 128x128 MFMA GEMM + split-K (gridDim.z) ----------------
// Cpart[ks][m][n]: partial over K-slab ks. A: MxK (row stride Ktot), B: NxK.
__global__ __launch_bounds__(256) void gemm128(const u16* __restrict__ A,
                                               const u16* __restrict__ B,
                                               float* __restrict__ Cp, size_t pstride, int N,
                                               int Ktot) {
  __shared__ u16 sA[128 * 32];
  __shared__ u16 sB[128 * 32];
  const int tid = threadIdx.x;
  const int wave = tid >> 6;
  const int lane = tid & 63;
  const int wr = wave >> 1;           // 2x2 wave grid, each wave 64x64
  const int wc = wave & 1;
  const int m0 = blockIdx.x * 128;
  const int n0 = blockIdx.y * 128;
  const int ks = blockIdx.z;
  const int Kper = Ktot / gridDim.z;
  const int kb = ks * Kper;
  const int row_l = tid >> 2;         // 0..63
  const int c8 = (tid & 3) << 3;      // granule offset (elems)
  const int frow = lane & 15;
  const int fcol = (lane >> 4) << 3;

  f32x4 acc[4][4];
#pragma unroll
  for (int i = 0; i < 4; ++i)
#pragma unroll
    for (int j = 0; j < 4; ++j) acc[i][j] = (f32x4){0.f, 0.f, 0.f, 0.f};

  for (int k0 = kb; k0 < kb + Kper; k0 += 32) {
    // async stage: dest = base + lane*16B; layout == row-major [128][32] (offset 16*tid B)
#pragma unroll
    for (int j = 0; j < 2; ++j) {
      gl_lds16(A + (size_t)(m0 + j * 64 + row_l) * Ktot + (k0 + c8), sA + j * 2048 + wave * 512);
      gl_lds16(B + (size_t)(n0 + j * 64 + row_l) * Ktot + (k0 + c8), sB + j * 2048 + wave * 512);
    }
    asm volatile("s_waitcnt vmcnt(0)" ::: "memory");
    __syncthreads();
    short8 af[4], bfr[4];
#pragma unroll
    for (int i = 0; i < 4; ++i)
      af[i] = *(const short8*)(sA + (wr * 64 + i * 16 + frow) * 32 + fcol);
#pragma unroll
    for (int j = 0; j < 4; ++j)
      bfr[j] = *(const short8*)(sB + (wc * 64 + j * 16 + frow) * 32 + fcol);
#pragma unroll
    for (int i = 0; i < 4; ++i)
#pragma unroll
      for (int j = 0; j < 4; ++j)
        acc[i][j] = __builtin_amdgcn_mfma_f32_16x16x32_bf16(af[i], bfr[j], acc[i][j], 0, 0, 0);
    __syncthreads();
  }
#pragma unroll
  for (int i = 0; i < 4; ++i) {
    const int rbase = m0 + wr * 64 + i * 16 + ((lane >> 4) << 2);
#pragma unroll
    for (int j = 0; j < 4; ++j) {
      const int col = n0 + wc * 64 + j * 16 + (lane & 15);
#pragma unroll
      for (int rg = 0; rg < 4; ++rg)
        Cp[(size_t)ks * pstride + (size_t)(rbase + rg) * N + col] = acc[i][j][rg];
    }
  }
}

// ---------------- p/q prep ----------------
__global__ void prep_pq(const float* __restrict__ trct, float* __restrict__ p,
                        float* __restrict__ q) {
  int t = blockIdx.x;
  int lane = threadIdx.x;  // 64
  float tr = trct[t * 128 + lane];
  float ct = trct[t * 128 + 64 + lane];
  float ap = fabsf(tr), aq = fabsf(ct);
  float Sp = wave_sum(ap);
  float Sq = wave_sum(aq);
  float denom = 1e-8f + Sp * Sq;
  p[t * 64 + lane] = ap;
  q[t * 64 + lane] = aq / denom;
}

// ---------------- scan phase 1 ----------------
__global__ void scan_phase1(const float* __restrict__ p, const float* __restrict__ q,
                            const unsigned char* __restrict__ st8, const int* __restrict__ st32,
                            const int* __restrict__ modep, const float* __restrict__ a,
                            const float* __restrict__ b, float4* __restrict__ chunkbuf) {
  int chunk = blockIdx.x, r = blockIdx.y, c = threadIdx.x;
  int mode = modep[0];
  float rho = expf(-fabsf(a[r]));
  float bb = b[c];
  float er = rho * cosf(bb), ei = rho * sinf(bb);
  float Ar = 1.f, Ai = 0.f, Br = 0.f, Bi = 0.f;
  int t0 = chunk * CLEN;
  for (int i = 0; i < CLEN; ++i) {
    int t = t0 + i;
    float qt = q[t * 64 + c];
    float pt = p[t * 64 + r];
    int st = read_start(st8, st32, mode, t);
    float pre = pt * qt;
    float cer = st ? 0.f : er;
    float cei = st ? 0.f : ei;
    float nAr = cer * Ar - cei * Ai;
    Ai = cer * Ai + cei * Ar;
    Ar = nAr;
    float nBr = cer * Br - cei * Bi + pre;
    Bi = cer * Bi + cei * Br;
    Br = nBr;
  }
  chunkbuf[((size_t)chunk * 64 + r) * 64 + c] = make_float4(Ar, Ai, Br, Bi);
}

// ---------------- scan phase 2 ----------------
__global__ void scan_phase2(const float4* __restrict__ chunkbuf, const float* __restrict__ state,
                            float2* __restrict__ s0buf) {
  int r = blockIdx.x, c = threadIdx.x;
  float Sr = state[r * 64 + c], Si = 0.f;
  for (int k = 0; k < NCHUNK; ++k) {
    s0buf[((size_t)k * 64 + r) * 64 + c] = make_float2(Sr, Si);
    float4 ab = chunkbuf[((size_t)k * 64 + r) * 64 + c];
    float nSr = ab.x * Sr - ab.y * Si + ab.z;
    Si = ab.x * Si + ab.y * Sr + ab.w;
    Sr = nSr;
  }
}

// ---------------- scan phase 3: emit log-polar features (bf16 bits) ----------------
__global__ void scan_phase3(const float* __restrict__ p, const float* __restrict__ q,
                            const unsigned char* __restrict__ st8, const int* __restrict__ st32,
                            const int* __restrict__ modep, const float* __restrict__ a,
                            const float* __restrict__ b, const float2* __restrict__ s0buf,
                            u16* __restrict__ scaled, int c0) {
  int chunk = c0 + blockIdx.x, r = blockIdx.y, c = threadIdx.x;
  int mode = modep[0];
  float rho = expf(-fabsf(a[r]));
  float bb = b[c];
  float er = rho * cosf(bb), ei = rho * sinf(bb);
  float2 s0 = s0buf[((size_t)chunk * 64 + r) * 64 + c];
  float Sr = s0.x, Si = s0.y;
  int t0 = chunk * CLEN;
  int tl0 = (chunk - c0) * CLEN;
  for (int i = 0; i < CLEN; ++i) {
    int t = t0 + i;
    float qt = q[t * 64 + c];
    float pt = p[t * 64 + r];
    int st = read_start(st8, st32, mode, t);
    float pre = pt * qt;
    float cer = st ? 0.f : er;
    float cei = st ? 0.f : ei;
    float nSr = cer * Sr - cei * Si + pre;
    Si = cer * Si + cei * Sr;
    Sr = nSr;
    float m2 = Sr * Sr + Si * Si;
    float m = sqrtf(m2);
    float mag = log1pf(m);
    float sc = mag / fmaxf(m, 1e-30f);
    size_t base = (size_t)(tl0 + i) * F_DIM + r * 64 + c;
    scaled[base] = f2bf_bits(sc * Si);
    scaled[base + 4096] = f2bf_bits(sc * Sr);
  }
}

// ---------------- LayerNorm + LeakyReLU over summed split-K partials ----------------
__global__ void ln_act(const float* __restrict__ parts, int KS, size_t pstride,
                       const float* __restrict__ bias, const float* __restrict__ gam,
                       const float* __restrict__ bet, u16* __restrict__ zbf,
                       const float* __restrict__ xsrc, float* __restrict__ xdst,
                       u16* __restrict__ xbf_next, float* __restrict__ finout) {
  __shared__ float red[8];
  int t = blockIdx.x, tid = threadIdx.x;
  size_t o = (size_t)t * D_DIM + tid;
  float v0 = bias[tid];
  float v1 = bias[tid + 256];
  for (int ks = 0; ks < KS; ++ks) {
    v0 += parts[(size_t)ks * pstride + o];
    v1 += parts[(size_t)ks * pstride + o + 256];
  }
  float s = wave_sum(v0 + v1);
  if ((tid & 63) == 0) red[tid >> 6] = s;
  __syncthreads();
  float mean = (red[0] + red[1] + red[2] + red[3]) * (1.f / 512.f);
  float d0 = v0 - mean, d1 = v1 - mean;
  float s2 = wave_sum(d0 * d0 + d1 * d1);
  if ((tid & 63) == 0) red[4 + (tid >> 6)] = s2;
  __syncthreads();
  float var = (red[4] + red[5] + red[6] + red[7]) * (1.f / 512.f);
  float rstd = rsqrtf(var + 1e-5f);
  float z0 = d0 * rstd * gam[tid] + bet[tid];
  float z1 = d1 * rstd * gam[tid + 256] + bet[tid + 256];
  z0 = z0 > 0.f ? z0 : 0.01f * z0;
  z1 = z1 > 0.f ? z1 : 0.01f * z1;
  if (zbf) { zbf[o] = f2bf_bits(z0); zbf[o + 256] = f2bf_bits(z1); }
  if (xdst) {
    float x0 = xsrc[o] + z0, x1 = xsrc[o + 256] + z1;
    xdst[o] = x0; xdst[o + 256] = x1;
    if (xbf_next) { xbf_next[o] = f2bf_bits(x0); xbf_next[o + 256] = f2bf_bits(x1); }
  }
  if (finout) { finout[o] = z0; finout[o + 256] = z1; }
}

__global__ void err_signal(float* __restrict__ out, float code) {
  if (threadIdx.x == 0) out[0] = code;
}

// ---------------- host launch ----------------
extern "C" void kernel_launch(void* const* d_in, const int* in_sizes, int n_in, void* d_out,
                              int out_size, void* d_ws, size_t ws_size, hipStream_t stream) {
  const float* x_in = (const float*)d_in[0];
  const float* state = (const float*)d_in[1];
  const unsigned char* start8 = (const unsigned char*)d_in[2];
  const int* start32 = (const int*)d_in[2];
  const float* Wtr = (const float*)d_in[3];
  const float* Wc = (const float*)d_in[4];
  const float* a_in = (const float*)d_in[5];
  const float* b_in = (const float*)d_in[6];
  const float* W0 = (const float*)d_in[7];
  const float* b0 = (const float*)d_in[8];
  const float* g0 = (const float*)d_in[9];
  const float* beta0 = (const float*)d_in[10];
  const float* W1 = (const float*)d_in[11];
  const float* b1 = (const float*)d_in[12];
  const float* g1 = (const float*)d_in[13];
  const float* beta1 = (const float*)d_in[14];
  float* out = (float*)d_out;

  char* w = (char*)d_ws;
  auto alloc = [&](size_t bytes) {
    char* ptr = w;
    w += (bytes + 255) & ~(size_t)255;
    return ptr;
  };
  float* x_ws = (float*)alloc(4ull * T_LEN * D_DIM);            // 8 MB
  u16* xbf = (u16*)alloc(2ull * T_LEN * D_DIM);                 // 4 MB
  u16* wcat = (u16*)alloc(2ull * 128 * D_DIM);                  // 128 KB
  u16* w0bf = (u16*)alloc(2ull * D_DIM * F_DIM);                // 8 MB (per-layer)
  u16* w1bf = (u16*)alloc(2ull * 3 * D_DIM * D_DIM);            // 1.5 MB (all layers)
  float* trct = (float*)alloc(4ull * T_LEN * 128);              // 2 MB
  float* pbuf = (float*)alloc(4ull * T_LEN * 64);               // 1 MB
  float* qbuf = (float*)alloc(4ull * T_LEN * 64);               // 1 MB
  float4* chunkbuf = (float4*)alloc(16ull * NCHUNK * 64 * 64);  // 4 MB
  float2* s0buf = (float2*)alloc(8ull * NCHUNK * 64 * 64);      // 2 MB
  u16* z0bf = (u16*)alloc(2ull * T_LEN * D_DIM);                // 4 MB
  int* modep = (int*)alloc(256);
  size_t base1 = (size_t)(w - (char*)d_ws);

  if (n_in != 15) {
    err_signal<<<1, 64, 0, stream>>>(out, 9e6f + 1000.f * n_in);
    return;
  }
  const size_t MB = 1ull << 20;
  int KS, nseg;
  if (ws_size >= base1 + 32 * MB + 64 * MB) { KS = 4; nseg = 1; }
  else if (ws_size >= base1 + 32 * MB + 32 * MB) { KS = 4; nseg = 2; }
  else if (ws_size >= base1 + 16 * MB + 32 * MB) { KS = 2; nseg = 2; }
  else if (ws_size >= base1 + 16 * MB + 16 * MB) { KS = 2; nseg = 4; }
  else if (ws_size >= base1 + 8 * MB + 16 * MB) { KS = 1; nseg = 4; }
  else {
    err_signal<<<1, 64, 0, stream>>>(out, 9e6f);
    return;
  }
  const int KSw1 = (KS >= 2) ? 2 : 1;
  const int seg_rows = T_LEN / nseg;
  const int seg_chunks = NCHUNK / nseg;
  const size_t pstride = (size_t)T_LEN * D_DIM;
  float* ypart = (float*)alloc(4ull * KS * pstride);
  u16* scaled = (u16*)alloc(2ull * seg_rows * F_DIM);

  detect_start<<<1, 256, 0, stream>>>(start8, modep);
  f2bf<<<(T_LEN * D_DIM) / 256, 256, 0, stream>>>(x_in, xbf, T_LEN * D_DIM);
  f2bf<<<(3 * D_DIM * D_DIM) / 256, 256, 0, stream>>>(W1, w1bf, 3 * D_DIM * D_DIM);

  for (int l = 0; l < 3; ++l) {
    const float* Wtr_l = Wtr + (size_t)l * 64 * D_DIM;
    const float* Wc_l = Wc + (size_t)l * 64 * D_DIM;
    const float* a_l = a_in + l * 64;
    const float* b_l = b_in + l * 64;
    const float* W0_l = W0 + (size_t)l * D_DIM * F_DIM;
    const u16* w1bf_l = w1bf + (size_t)l * D_DIM * D_DIM;
    const float* state_l = state + (size_t)l * 64 * 64;
    const float* xsrc = (l == 0) ? x_in : x_ws;

    k_wcat<<<(128 * D_DIM) / 256, 256, 0, stream>>>(Wtr_l, Wc_l, wcat);
    f2bf<<<(D_DIM * F_DIM) / 256, 256, 0, stream>>>(W0_l, w0bf, D_DIM * F_DIM);

    // trct (4096 x 128) = xbf @ wcat^T
    gemm_bt<64, 64, 2, 2><<<dim3(T_LEN / 64, 2), 256, 0, stream>>>(xbf, wcat, trct, T_LEN, 128,
                                                                   D_DIM);
    prep_pq<<<T_LEN, 64, 0, stream>>>(trct, pbuf, qbuf);
    scan_phase1<<<dim3(NCHUNK, 64), 64, 0, stream>>>(pbuf, qbuf, start8, start32, modep, a_l,
                                                     b_l, chunkbuf);
    scan_phase2<<<64, 64, 0, stream>>>(chunkbuf, state_l, s0buf);

    for (int h = 0; h < nseg; ++h) {
      scan_phase3<<<dim3(seg_chunks, 64), 64, 0, stream>>>(pbuf, qbuf, start8, start32, modep,
                                                           a_l, b_l, s0buf, scaled,
                                                           h * seg_chunks);
      // y(seg) = scaled (seg_rows x 8192) @ W0^T, split-K partials into ypart
      gemm128<<<dim3(seg_rows / 128, D_DIM / 128, KS), 256, 0, stream>>>(
          scaled, w0bf, ypart + (size_t)h * seg_rows * D_DIM, pstride, D_DIM, F_DIM);
    }
    ln_act<<<T_LEN, 256, 0, stream>>>(ypart, KS, pstride, b0 + l * D_DIM, g0 + l * D_DIM,
                                      beta0 + l * D_DIM, z0bf, nullptr, nullptr, nullptr,
                                      nullptr);
    // y2 = z0 @ W1^T (split-K KSw1)
    gemm128<<<dim3(T_LEN / 128, D_DIM / 128, KSw1), 256, 0, stream>>>(z0bf, w1bf_l, ypart,
                                                                      pstride, D_DIM, D_DIM);
    ln_act<<<T_LEN, 256, 0, stream>>>(ypart, KSw1, pstride, b1 + l * D_DIM, g1 + l * D_DIM,
                                      beta1 + l * D_DIM, nullptr, (l < 2) ? xsrc : nullptr,
                                      (l < 2) ? x_ws : nullptr, (l < 2) ? xbf : nullptr,
                                      (l == 2) ? out : nullptr);
  }
}

// Round 8
// 554.568 us; speedup vs baseline: 5.9184x; 1.3566x over previous
//
#include <hip/hip_runtime.h>
#include <hip/hip_bf16.h>
#include <math.h>

#define T_LEN 4096
#define D_DIM 512
#define F_DIM 8192
#define NCHUNK 64
#define CLEN 64

typedef short short8 __attribute__((ext_vector_type(8)));
typedef float f32x4 __attribute__((ext_vector_type(4)));
typedef unsigned short u16;
typedef unsigned int u32;

// ---------------- helpers ----------------
__device__ inline float wave_sum(float v) {
#pragma unroll
  for (int o = 32; o; o >>= 1) v += __shfl_xor(v, o);
  return v;
}

__device__ inline u16 f2bf_bits(float v) {
  __hip_bfloat16 h = __float2bfloat16(v);
  return *(u16*)&h;
}

__device__ inline void gl_lds16(const void* g, void* l) {
  __builtin_amdgcn_global_load_lds((const __attribute__((address_space(1))) void*)g,
                                   (__attribute__((address_space(3))) void*)l, 16, 0, 0);
}

// start[] may arrive as 1-byte bools or int32 {0,1}.
__global__ void detect_start(const unsigned char* __restrict__ s8, int* __restrict__ mode) {
  __shared__ int found;
  if (threadIdx.x == 0) found = 0;
  __syncthreads();
  for (int i = threadIdx.x; i < 4096; i += 256)
    if ((i & 3) && s8[i]) found = 1;  // benign race, same value
  __syncthreads();
  if (threadIdx.x == 0) mode[0] = found;  // 1 = byte layout, 0 = int32 layout
}

__device__ inline int read_start(const unsigned char* s8, const int* s32, int mode, int t) {
  return mode ? (int)s8[t] : s32[t];
}

// ---------------- fp32 -> bf16(bits) convert ----------------
__global__ void f2bf(const float* __restrict__ s, u16* __restrict__ d, int n) {
  int i = blockIdx.x * 256 + threadIdx.x;
  if (i < n) d[i] = f2bf_bits(s[i]);
}

// W0 convert + K-permute: dst[d][r*128+2c+b] = W0[d][b*4096+r*64+c]
// (feature dim permuted to match scan_phase3's packed sin/cos interleave)
__global__ void k_w0perm(const float* __restrict__ src, u16* __restrict__ dst) {
  int i = blockIdx.x * 256 + threadIdx.x;  // over 512*8192
  int d = i >> 13, f = i & 8191;
  int r = f >> 7, rem = f & 127;
  int c = rem >> 1, b = rem & 1;
  dst[i] = f2bf_bits(src[(size_t)d * 8192 + b * 4096 + r * 64 + c]);
}

// concat [Wtr_l; Wc_l] -> (128 x 512) bf16
__global__ void k_wcat(const float* __restrict__ wtr, const float* __restrict__ wc,
                       u16* __restrict__ dst) {
  int i = blockIdx.x * 256 + threadIdx.x;  // n = 128*512
  float v = (i < 64 * D_DIM) ? wtr[i] : wc[i - 64 * D_DIM];
  dst[i] = f2bf_bits(v);
}

// ---------------- small MFMA GEMM (64x64 tile, sync staging) — used for trct ----------------
template <int BM, int BN, int WR, int WC>
__global__ __launch_bounds__(256) void gemm_bt(const u16* __restrict__ A,
                                               const u16* __restrict__ B,
                                               float* __restrict__ C, int M, int N, int K) {
  constexpr int BK = 32;
  constexpr int MT = BM / (WR * 16);
  constexpr int NT = BN / (WC * 16);
  constexpr int AG = BM / 64;
  constexpr int BG = BN / 64;
  __shared__ u16 sA[BM * BK];
  __shared__ u16 sB[BN * BK];
  const int m0 = blockIdx.x * BM;
  const int n0 = blockIdx.y * BN;
  const int tid = threadIdx.x;
  const int wave = tid >> 6;
  const int lane = tid & 63;
  const int wr = wave / WC;
  const int wc = wave % WC;
  const int row_l = tid >> 2;
  const int c8 = (tid & 3) << 3;
  const int frow = lane & 15;
  const int fcol = (lane >> 4) << 3;

  f32x4 acc[MT][NT];
#pragma unroll
  for (int i = 0; i < MT; ++i)
#pragma unroll
    for (int j = 0; j < NT; ++j) acc[i][j] = (f32x4){0.f, 0.f, 0.f, 0.f};

  for (int k0 = 0; k0 < K; k0 += BK) {
#pragma unroll
    for (int j = 0; j < AG; ++j) {
      uint4 v = *(const uint4*)(A + (size_t)(m0 + j * 64 + row_l) * K + (k0 + c8));
      *(uint4*)(sA + (j * 64 + row_l) * BK + c8) = v;
    }
#pragma unroll
    for (int j = 0; j < BG; ++j) {
      uint4 v = *(const uint4*)(B + (size_t)(n0 + j * 64 + row_l) * K + (k0 + c8));
      *(uint4*)(sB + (j * 64 + row_l) * BK + c8) = v;
    }
    __syncthreads();
    short8 af[MT], bfr[NT];
#pragma unroll
    for (int i = 0; i < MT; ++i)
      af[i] = *(const short8*)(sA + (wr * MT * 16 + i * 16 + frow) * BK + fcol);
#pragma unroll
    for (int j = 0; j < NT; ++j)
      bfr[j] = *(const short8*)(sB + (wc * NT * 16 + j * 16 + frow) * BK + fcol);
#pragma unroll
    for (int i = 0; i < MT; ++i)
#pragma unroll
      for (int j = 0; j < NT; ++j)
        acc[i][j] = __builtin_amdgcn_mfma_f32_16x16x32_bf16(af[i], bfr[j], acc[i][j], 0, 0, 0);
    __syncthreads();
  }
#pragma unroll
  for (int i = 0; i < MT; ++i) {
    const int rbase = m0 + wr * MT * 16 + i * 16 + ((lane >> 4) << 2);
#pragma unroll
    for (int j = 0; j < NT; ++j) {
      const int col = n0 + wc * NT * 16 + j * 16 + (lane & 15);
#pragma unroll
      for (int rg = 0; rg < 4; ++rg) C[(size_t)(rbase + rg) * N + col] = acc[i][j][rg];
    }
  }
}

// ---------------- m97-style 128x128 MFMA GEMM + split-K (gridDim.z) ----------------
__global__ __launch_bounds__(256) void gemm128(const u16* __restrict__ A,
                                               const u16* __restrict__ B,
                                               float* __restrict__ Cp, size_t pstride, int N,
                                               int Ktot) {
  __shared__ u16 sA[128 * 32];
  __shared__ u16 sB[128 * 32];
  const int tid = threadIdx.x;
  const int wave = tid >> 6;
  const int lane = tid & 63;
  const int wr = wave >> 1;
  const int wc = wave & 1;
  const int m0 = blockIdx.x * 128;
  const int n0 = blockIdx.y * 128;
  const int ks = blockIdx.z;
  const int Kper = Ktot / gridDim.z;
  const int kb = ks * Kper;
  const int row_l = tid >> 2;
  const int c8 = (tid & 3) << 3;
  const int frow = lane & 15;
  const int fcol = (lane >> 4) << 3;

  f32x4 acc[4][4];
#pragma unroll
  for (int i = 0; i < 4; ++i)
#pragma unroll
    for (int j = 0; j < 4; ++j) acc[i][j] = (f32x4){0.f, 0.f, 0.f, 0.f};

  for (int k0 = kb; k0 < kb + Kper; k0 += 32) {
#pragma unroll
    for (int j = 0; j < 2; ++j) {
      gl_lds16(A + (size_t)(m0 + j * 64 + row_l) * Ktot + (k0 + c8), sA + j * 2048 + wave * 512);
      gl_lds16(B + (size_t)(n0 + j * 64 + row_l) * Ktot + (k0 + c8), sB + j * 2048 + wave * 512);
    }
    asm volatile("s_waitcnt vmcnt(0)" ::: "memory");
    __syncthreads();
    short8 af[4], bfr[4];
#pragma unroll
    for (int i = 0; i < 4; ++i)
      af[i] = *(const short8*)(sA + (wr * 64 + i * 16 + frow) * 32 + fcol);
#pragma unroll
    for (int j = 0; j < 4; ++j)
      bfr[j] = *(const short8*)(sB + (wc * 64 + j * 16 + frow) * 32 + fcol);
#pragma unroll
    for (int i = 0; i < 4; ++i)
#pragma unroll
      for (int j = 0; j < 4; ++j)
        acc[i][j] = __builtin_amdgcn_mfma_f32_16x16x32_bf16(af[i], bfr[j], acc[i][j], 0, 0, 0);
    __syncthreads();
  }
#pragma unroll
  for (int i = 0; i < 4; ++i) {
    const int rbase = m0 + wr * 64 + i * 16 + ((lane >> 4) << 2);
#pragma unroll
    for (int j = 0; j < 4; ++j) {
      const int col = n0 + wc * 64 + j * 16 + (lane & 15);
#pragma unroll
      for (int rg = 0; rg < 4; ++rg)
        Cp[(size_t)ks * pstride + (size_t)(rbase + rg) * N + col] = acc[i][j][rg];
    }
  }
}

// ---------------- p/q prep: p=|tr| (both layouts), q=|ct|/(1e-8+Sp*Sq) ----------------
__global__ void prep_pq(const float* __restrict__ trct, float* __restrict__ p,
                        float* __restrict__ pT, float* __restrict__ q) {
  int t = blockIdx.x;
  int lane = threadIdx.x;  // 64
  float tr = trct[t * 128 + lane];
  float ct = trct[t * 128 + 64 + lane];
  float ap = fabsf(tr), aq = fabsf(ct);
  float Sp = wave_sum(ap);
  float Sq = wave_sum(aq);
  float denom = 1e-8f + Sp * Sq;
  p[t * 64 + lane] = ap;
  pT[lane * T_LEN + t] = ap;  // transposed copy for shuffle-broadcast in scans
  q[t * 64 + lane] = aq / denom;
}

// ---------------- scan phase 1: per-chunk affine summary (A,B) ----------------
__global__ void scan_phase1(const float* __restrict__ pT, const float* __restrict__ q,
                            const unsigned char* __restrict__ st8, const int* __restrict__ st32,
                            const int* __restrict__ modep, const float* __restrict__ a,
                            const float* __restrict__ b, float4* __restrict__ chunkbuf) {
  int chunk = blockIdx.x, r = blockIdx.y, c = threadIdx.x;
  int mode = modep[0];
  int t0 = chunk * CLEN;
  float rho = expf(-fabsf(a[r]));
  float bb = b[c];
  float er = rho * cosf(bb), ei = rho * sinf(bb);
  float pv = pT[r * T_LEN + t0 + c];            // lane c holds p for step c
  int sv = read_start(st8, st32, mode, t0 + c);  // lane c holds start for step c
  float Ar = 1.f, Ai = 0.f, Br = 0.f, Bi = 0.f;
  const float* qrow = q + (size_t)t0 * 64 + c;
#pragma unroll 8
  for (int i = 0; i < CLEN; ++i) {
    float qt = qrow[i * 64];
    float pt = __shfl(pv, i);
    int st = __shfl(sv, i);
    float pre = pt * qt;
    float cer = st ? 0.f : er;
    float cei = st ? 0.f : ei;
    float nAr = cer * Ar - cei * Ai;
    Ai = cer * Ai + cei * Ar;
    Ar = nAr;
    float nBr = cer * Br - cei * Bi + pre;
    Bi = cer * Bi + cei * Br;
    Br = nBr;
  }
  chunkbuf[((size_t)chunk * 64 + r) * 64 + c] = make_float4(Ar, Ai, Br, Bi);
}

// ---------------- scan phase 2: sequential chunk combine ----------------
__global__ void scan_phase2(const float4* __restrict__ chunkbuf, const float* __restrict__ state,
                            float2* __restrict__ s0buf) {
  int r = blockIdx.x, c = threadIdx.x;
  float Sr = state[r * 64 + c], Si = 0.f;
  for (int k = 0; k < NCHUNK; ++k) {
    s0buf[((size_t)k * 64 + r) * 64 + c] = make_float2(Sr, Si);
    float4 ab = chunkbuf[((size_t)k * 64 + r) * 64 + c];
    float nSr = ab.x * Sr - ab.y * Si + ab.z;
    Si = ab.x * Si + ab.y * Sr + ab.w;
    Sr = nSr;
  }
}

// ---------------- scan phase 3: replay + packed log-polar features ----------------
// scaled dword layout: [t][r*64+c] = (bf16(mag*cos) << 16) | bf16(mag*sin)
// i.e. feature index f = r*128 + 2c + {0=sin,1=cos}; W0 is permuted to match.
__global__ void scan_phase3(const float* __restrict__ pT, const float* __restrict__ q,
                            const unsigned char* __restrict__ st8, const int* __restrict__ st32,
                            const int* __restrict__ modep, const float* __restrict__ a,
                            const float* __restrict__ b, const float2* __restrict__ s0buf,
                            u32* __restrict__ scaled, int c0) {
  int chunk = c0 + blockIdx.x, r = blockIdx.y, c = threadIdx.x;
  int mode = modep[0];
  int t0 = chunk * CLEN;
  float rho = expf(-fabsf(a[r]));
  float bb = b[c];
  float er = rho * cosf(bb), ei = rho * sinf(bb);
  float pv = pT[r * T_LEN + t0 + c];
  int sv = read_start(st8, st32, mode, t0 + c);
  float2 s0 = s0buf[((size_t)chunk * 64 + r) * 64 + c];
  float Sr = s0.x, Si = s0.y;
  int tl0 = (chunk - c0) * CLEN;
  const float* qrow = q + (size_t)t0 * 64 + c;
  u32* drow = scaled + (size_t)tl0 * 4096 + r * 64 + c;
#pragma unroll 4
  for (int i = 0; i < CLEN; ++i) {
    float qt = qrow[i * 64];
    float pt = __shfl(pv, i);
    int st = __shfl(sv, i);
    float pre = pt * qt;
    float cer = st ? 0.f : er;
    float cei = st ? 0.f : ei;
    float nSr = cer * Sr - cei * Si + pre;
    Si = cer * Si + cei * Sr;
    Sr = nSr;
    // sc = log1p(m)/m via hw log2/rsq; rel err ~6e-4 << bf16 quantization
    float m2 = fmaf(Sr, Sr, Si * Si);
    float rsq = rsqrtf(fmaxf(m2, 1e-30f));
    float m = m2 * rsq;
    float sc = __log2f(1.0f + m) * 0.6931471805599453f * rsq;
    u32 pack = ((u32)f2bf_bits(sc * Sr) << 16) | (u32)f2bf_bits(sc * Si);
    drow[(size_t)i * 4096] = pack;
  }
}

// ---------------- LayerNorm + LeakyReLU over summed split-K partials ----------------
__global__ void ln_act(const float* __restrict__ parts, int KS, size_t pstride,
                       const float* __restrict__ bias, const float* __restrict__ gam,
                       const float* __restrict__ bet, u16* __restrict__ zbf,
                       const float* __restrict__ xsrc, float* __restrict__ xdst,
                       u16* __restrict__ xbf_next, float* __restrict__ finout) {
  __shared__ float red[8];
  int t = blockIdx.x, tid = threadIdx.x;
  size_t o = (size_t)t * D_DIM + tid;
  float v0 = bias[tid];
  float v1 = bias[tid + 256];
  for (int ks = 0; ks < KS; ++ks) {
    v0 += parts[(size_t)ks * pstride + o];
    v1 += parts[(size_t)ks * pstride + o + 256];
  }
  float s = wave_sum(v0 + v1);
  if ((tid & 63) == 0) red[tid >> 6] = s;
  __syncthreads();
  float mean = (red[0] + red[1] + red[2] + red[3]) * (1.f / 512.f);
  float d0 = v0 - mean, d1 = v1 - mean;
  float s2 = wave_sum(d0 * d0 + d1 * d1);
  if ((tid & 63) == 0) red[4 + (tid >> 6)] = s2;
  __syncthreads();
  float var = (red[4] + red[5] + red[6] + red[7]) * (1.f / 512.f);
  float rstd = rsqrtf(var + 1e-5f);
  float z0 = d0 * rstd * gam[tid] + bet[tid];
  float z1 = d1 * rstd * gam[tid + 256] + bet[tid + 256];
  z0 = z0 > 0.f ? z0 : 0.01f * z0;
  z1 = z1 > 0.f ? z1 : 0.01f * z1;
  if (zbf) { zbf[o] = f2bf_bits(z0); zbf[o + 256] = f2bf_bits(z1); }
  if (xdst) {
    float x0 = xsrc[o] + z0, x1 = xsrc[o + 256] + z1;
    xdst[o] = x0; xdst[o + 256] = x1;
    if (xbf_next) { xbf_next[o] = f2bf_bits(x0); xbf_next[o + 256] = f2bf_bits(x1); }
  }
  if (finout) { finout[o] = z0; finout[o + 256] = z1; }
}

__global__ void err_signal(float* __restrict__ out, float code) {
  if (threadIdx.x == 0) out[0] = code;
}

// ---------------- host launch ----------------
extern "C" void kernel_launch(void* const* d_in, const int* in_sizes, int n_in, void* d_out,
                              int out_size, void* d_ws, size_t ws_size, hipStream_t stream) {
  const float* x_in = (const float*)d_in[0];
  const float* state = (const float*)d_in[1];
  const unsigned char* start8 = (const unsigned char*)d_in[2];
  const int* start32 = (const int*)d_in[2];
  const float* Wtr = (const float*)d_in[3];
  const float* Wc = (const float*)d_in[4];
  const float* a_in = (const float*)d_in[5];
  const float* b_in = (const float*)d_in[6];
  const float* W0 = (const float*)d_in[7];
  const float* b0 = (const float*)d_in[8];
  const float* g0 = (const float*)d_in[9];
  const float* beta0 = (const float*)d_in[10];
  const float* W1 = (const float*)d_in[11];
  const float* b1 = (const float*)d_in[12];
  const float* g1 = (const float*)d_in[13];
  const float* beta1 = (const float*)d_in[14];
  float* out = (float*)d_out;

  char* w = (char*)d_ws;
  auto alloc = [&](size_t bytes) {
    char* ptr = w;
    w += (bytes + 255) & ~(size_t)255;
    return ptr;
  };
  float* x_ws = (float*)alloc(4ull * T_LEN * D_DIM);            // 8 MB
  u16* xbf = (u16*)alloc(2ull * T_LEN * D_DIM);                 // 4 MB
  u16* wcat = (u16*)alloc(2ull * 128 * D_DIM);                  // 128 KB
  u16* w0bf = (u16*)alloc(2ull * D_DIM * F_DIM);                // 8 MB (per-layer)
  u16* w1bf = (u16*)alloc(2ull * 3 * D_DIM * D_DIM);            // 1.5 MB (all layers)
  float* trct = (float*)alloc(4ull * T_LEN * 128);              // 2 MB
  float* pbuf = (float*)alloc(4ull * T_LEN * 64);               // 1 MB
  float* pTbuf = (float*)alloc(4ull * T_LEN * 64);              // 1 MB
  float* qbuf = (float*)alloc(4ull * T_LEN * 64);               // 1 MB
  float4* chunkbuf = (float4*)alloc(16ull * NCHUNK * 64 * 64);  // 4 MB
  float2* s0buf = (float2*)alloc(8ull * NCHUNK * 64 * 64);      // 2 MB
  u16* z0bf = (u16*)alloc(2ull * T_LEN * D_DIM);                // 4 MB
  int* modep = (int*)alloc(256);
  size_t base1 = (size_t)(w - (char*)d_ws);

  if (n_in != 15) {
    err_signal<<<1, 64, 0, stream>>>(out, 9e6f + 1000.f * n_in);
    return;
  }
  const size_t MB = 1ull << 20;
  int KS, nseg;
  if (ws_size >= base1 + 32 * MB + 64 * MB) { KS = 4; nseg = 1; }
  else if (ws_size >= base1 + 32 * MB + 32 * MB) { KS = 4; nseg = 2; }
  else if (ws_size >= base1 + 16 * MB + 32 * MB) { KS = 2; nseg = 2; }
  else if (ws_size >= base1 + 16 * MB + 16 * MB) { KS = 2; nseg = 4; }
  else if (ws_size >= base1 + 8 * MB + 16 * MB) { KS = 1; nseg = 4; }
  else {
    err_signal<<<1, 64, 0, stream>>>(out, 9e6f);
    return;
  }
  const int KSw1 = (KS >= 2) ? 2 : 1;
  const int seg_rows = T_LEN / nseg;
  const int seg_chunks = NCHUNK / nseg;
  const size_t pstride = (size_t)T_LEN * D_DIM;
  float* ypart = (float*)alloc(4ull * KS * pstride);
  u16* scaled = (u16*)alloc(2ull * seg_rows * F_DIM);

  detect_start<<<1, 256, 0, stream>>>(start8, modep);
  f2bf<<<(T_LEN * D_DIM) / 256, 256, 0, stream>>>(x_in, xbf, T_LEN * D_DIM);
  f2bf<<<(3 * D_DIM * D_DIM) / 256, 256, 0, stream>>>(W1, w1bf, 3 * D_DIM * D_DIM);

  for (int l = 0; l < 3; ++l) {
    const float* Wtr_l = Wtr + (size_t)l * 64 * D_DIM;
    const float* Wc_l = Wc + (size_t)l * 64 * D_DIM;
    const float* a_l = a_in + l * 64;
    const float* b_l = b_in + l * 64;
    const float* W0_l = W0 + (size_t)l * D_DIM * F_DIM;
    const u16* w1bf_l = w1bf + (size_t)l * D_DIM * D_DIM;
    const float* state_l = state + (size_t)l * 64 * 64;
    const float* xsrc = (l == 0) ? x_in : x_ws;

    k_wcat<<<(128 * D_DIM) / 256, 256, 0, stream>>>(Wtr_l, Wc_l, wcat);
    k_w0perm<<<(D_DIM * F_DIM) / 256, 256, 0, stream>>>(W0_l, w0bf);

    // trct (4096 x 128) = xbf @ wcat^T
    gemm_bt<64, 64, 2, 2><<<dim3(T_LEN / 64, 2), 256, 0, stream>>>(xbf, wcat, trct, T_LEN, 128,
                                                                   D_DIM);
    prep_pq<<<T_LEN, 64, 0, stream>>>(trct, pbuf, pTbuf, qbuf);
    scan_phase1<<<dim3(NCHUNK, 64), 64, 0, stream>>>(pTbuf, qbuf, start8, start32, modep, a_l,
                                                     b_l, chunkbuf);
    scan_phase2<<<64, 64, 0, stream>>>(chunkbuf, state_l, s0buf);

    for (int h = 0; h < nseg; ++h) {
      scan_phase3<<<dim3(seg_chunks, 64), 64, 0, stream>>>(pTbuf, qbuf, start8, start32, modep,
                                                           a_l, b_l, s0buf, (u32*)scaled,
                                                           h * seg_chunks);
      gemm128<<<dim3(seg_rows / 128, D_DIM / 128, KS), 256, 0, stream>>>(
          scaled, w0bf, ypart + (size_t)h * seg_rows * D_DIM, pstride, D_DIM, F_DIM);
    }
    ln_act<<<T_LEN, 256, 0, stream>>>(ypart, KS, pstride, b0 + l * D_DIM, g0 + l * D_DIM,
                                      beta0 + l * D_DIM, z0bf, nullptr, nullptr, nullptr,
                                      nullptr);
    gemm128<<<dim3(T_LEN / 128, D_DIM / 128, KSw1), 256, 0, stream>>>(z0bf, w1bf_l, ypart,
                                                                      pstride, D_DIM, D_DIM);
    ln_act<<<T_LEN, 256, 0, stream>>>(ypart, KSw1, pstride, b1 + l * D_DIM, g1 + l * D_DIM,
                                      beta1 + l * D_DIM, nullptr, (l < 2) ? xsrc : nullptr,
                                      (l < 2) ? x_ws : nullptr, (l < 2) ? xbf : nullptr,
                                      (l == 2) ? out : nullptr);
  }
}

// Round 9
// 549.618 us; speedup vs baseline: 5.9717x; 1.0090x over previous
//
#include <hip/hip_runtime.h>
#include <hip/hip_bf16.h>
#include <math.h>

#define T_LEN 4096
#define D_DIM 512
#define F_DIM 8192
#define NCHUNK 64
#define CLEN 64

typedef short short8 __attribute__((ext_vector_type(8)));
typedef float f32x4 __attribute__((ext_vector_type(4)));
typedef unsigned short u16;
typedef unsigned int u32;

// ---------------- helpers ----------------
__device__ inline float wave_sum(float v) {
#pragma unroll
  for (int o = 32; o; o >>= 1) v += __shfl_xor(v, o);
  return v;
}

__device__ inline u16 f2bf_bits(float v) {
  __hip_bfloat16 h = __float2bfloat16(v);
  return *(u16*)&h;
}

__device__ inline void gl_lds16(const void* g, void* l) {
  __builtin_amdgcn_global_load_lds((const __attribute__((address_space(1))) void*)g,
                                   (__attribute__((address_space(3))) void*)l, 16, 0, 0);
}

// start[] may arrive as 1-byte bools or int32 {0,1}.
__global__ void detect_start(const unsigned char* __restrict__ s8, int* __restrict__ mode) {
  __shared__ int found;
  if (threadIdx.x == 0) found = 0;
  __syncthreads();
  for (int i = threadIdx.x; i < 4096; i += 256)
    if ((i & 3) && s8[i]) found = 1;  // benign race, same value
  __syncthreads();
  if (threadIdx.x == 0) mode[0] = found;  // 1 = byte layout, 0 = int32 layout
}

__device__ inline int read_start(const unsigned char* s8, const int* s32, int mode, int t) {
  return mode ? (int)s8[t] : s32[t];
}

// ---------------- fp32 -> bf16(bits) convert ----------------
__global__ void f2bf(const float* __restrict__ s, u16* __restrict__ d, int n) {
  int i = blockIdx.x * 256 + threadIdx.x;
  if (i < n) d[i] = f2bf_bits(s[i]);
}

// fused per-layer weight conversion:
//   [0, 65536): wcat = concat [Wtr_l; Wc_l] (128 x 512)
//   [65536, 65536+4194304): w0bf with K-permute dst[d][r*128+2c+b] = W0[d][b*4096+r*64+c]
__global__ void k_conv(const float* __restrict__ wtr, const float* __restrict__ wc,
                       u16* __restrict__ wcat, const float* __restrict__ w0,
                       u16* __restrict__ w0bf) {
  int i = blockIdx.x * 256 + threadIdx.x;
  if (i < 128 * D_DIM) {
    float v = (i < 64 * D_DIM) ? wtr[i] : wc[i - 64 * D_DIM];
    wcat[i] = f2bf_bits(v);
  }
  int j = i - 128 * D_DIM;
  if (j >= 0 && j < D_DIM * F_DIM) {
    int d = j >> 13, f = j & 8191;
    int r = f >> 7, rem = f & 127;
    int c = rem >> 1, b = rem & 1;
    w0bf[j] = f2bf_bits(w0[(size_t)d * 8192 + b * 4096 + r * 64 + c]);
  }
}

// ---------------- small MFMA GEMM (64x64 tile, sync staging) — used for trct ----------------
template <int BM, int BN, int WR, int WC>
__global__ __launch_bounds__(256) void gemm_bt(const u16* __restrict__ A,
                                               const u16* __restrict__ B,
                                               float* __restrict__ C, int M, int N, int K) {
  constexpr int BK = 32;
  constexpr int MT = BM / (WR * 16);
  constexpr int NT = BN / (WC * 16);
  constexpr int AG = BM / 64;
  constexpr int BG = BN / 64;
  __shared__ u16 sA[BM * BK];
  __shared__ u16 sB[BN * BK];
  const int m0 = blockIdx.x * BM;
  const int n0 = blockIdx.y * BN;
  const int tid = threadIdx.x;
  const int wave = tid >> 6;
  const int lane = tid & 63;
  const int wr = wave / WC;
  const int wc = wave % WC;
  const int row_l = tid >> 2;
  const int c8 = (tid & 3) << 3;
  const int frow = lane & 15;
  const int fcol = (lane >> 4) << 3;

  f32x4 acc[MT][NT];
#pragma unroll
  for (int i = 0; i < MT; ++i)
#pragma unroll
    for (int j = 0; j < NT; ++j) acc[i][j] = (f32x4){0.f, 0.f, 0.f, 0.f};

  for (int k0 = 0; k0 < K; k0 += BK) {
#pragma unroll
    for (int j = 0; j < AG; ++j) {
      uint4 v = *(const uint4*)(A + (size_t)(m0 + j * 64 + row_l) * K + (k0 + c8));
      *(uint4*)(sA + (j * 64 + row_l) * BK + c8) = v;
    }
#pragma unroll
    for (int j = 0; j < BG; ++j) {
      uint4 v = *(const uint4*)(B + (size_t)(n0 + j * 64 + row_l) * K + (k0 + c8));
      *(uint4*)(sB + (j * 64 + row_l) * BK + c8) = v;
    }
    __syncthreads();
    short8 af[MT], bfr[NT];
#pragma unroll
    for (int i = 0; i < MT; ++i)
      af[i] = *(const short8*)(sA + (wr * MT * 16 + i * 16 + frow) * BK + fcol);
#pragma unroll
    for (int j = 0; j < NT; ++j)
      bfr[j] = *(const short8*)(sB + (wc * NT * 16 + j * 16 + frow) * BK + fcol);
#pragma unroll
    for (int i = 0; i < MT; ++i)
#pragma unroll
      for (int j = 0; j < NT; ++j)
        acc[i][j] = __builtin_amdgcn_mfma_f32_16x16x32_bf16(af[i], bfr[j], acc[i][j], 0, 0, 0);
    __syncthreads();
  }
#pragma unroll
  for (int i = 0; i < MT; ++i) {
    const int rbase = m0 + wr * MT * 16 + i * 16 + ((lane >> 4) << 2);
#pragma unroll
    for (int j = 0; j < NT; ++j) {
      const int col = n0 + wc * NT * 16 + j * 16 + (lane & 15);
#pragma unroll
      for (int rg = 0; rg < 4; ++rg) C[(size_t)(rbase + rg) * N + col] = acc[i][j][rg];
    }
  }
}

// ---------------- m97-style 128x128 MFMA GEMM + split-K (gridDim.z) ----------------
__global__ __launch_bounds__(256) void gemm128(const u16* __restrict__ A,
                                               const u16* __restrict__ B,
                                               float* __restrict__ Cp, size_t pstride, int N,
                                               int Ktot) {
  __shared__ u16 sA[128 * 32];
  __shared__ u16 sB[128 * 32];
  const int tid = threadIdx.x;
  const int wave = tid >> 6;
  const int lane = tid & 63;
  const int wr = wave >> 1;
  const int wc = wave & 1;
  const int m0 = blockIdx.x * 128;
  const int n0 = blockIdx.y * 128;
  const int ks = blockIdx.z;
  const int Kper = Ktot / gridDim.z;
  const int kb = ks * Kper;
  const int row_l = tid >> 2;
  const int c8 = (tid & 3) << 3;
  const int frow = lane & 15;
  const int fcol = (lane >> 4) << 3;

  f32x4 acc[4][4];
#pragma unroll
  for (int i = 0; i < 4; ++i)
#pragma unroll
    for (int j = 0; j < 4; ++j) acc[i][j] = (f32x4){0.f, 0.f, 0.f, 0.f};

  for (int k0 = kb; k0 < kb + Kper; k0 += 32) {
#pragma unroll
    for (int j = 0; j < 2; ++j) {
      gl_lds16(A + (size_t)(m0 + j * 64 + row_l) * Ktot + (k0 + c8), sA + j * 2048 + wave * 512);
      gl_lds16(B + (size_t)(n0 + j * 64 + row_l) * Ktot + (k0 + c8), sB + j * 2048 + wave * 512);
    }
    asm volatile("s_waitcnt vmcnt(0)" ::: "memory");
    __syncthreads();
    short8 af[4], bfr[4];
#pragma unroll
    for (int i = 0; i < 4; ++i)
      af[i] = *(const short8*)(sA + (wr * 64 + i * 16 + frow) * 32 + fcol);
#pragma unroll
    for (int j = 0; j < 4; ++j)
      bfr[j] = *(const short8*)(sB + (wc * 64 + j * 16 + frow) * 32 + fcol);
#pragma unroll
    for (int i = 0; i < 4; ++i)
#pragma unroll
      for (int j = 0; j < 4; ++j)
        acc[i][j] = __builtin_amdgcn_mfma_f32_16x16x32_bf16(af[i], bfr[j], acc[i][j], 0, 0, 0);
    __syncthreads();
  }
#pragma unroll
  for (int i = 0; i < 4; ++i) {
    const int rbase = m0 + wr * 64 + i * 16 + ((lane >> 4) << 2);
#pragma unroll
    for (int j = 0; j < 4; ++j) {
      const int col = n0 + wc * 64 + j * 16 + (lane & 15);
#pragma unroll
      for (int rg = 0; rg < 4; ++rg)
        Cp[(size_t)ks * pstride + (size_t)(rbase + rg) * N + col] = acc[i][j][rg];
    }
  }
}

// ---------------- p/q prep: pT=|tr| transposed, q=|ct|/(1e-8+Sp*Sq) ----------------
__global__ void prep_pq(const float* __restrict__ trct, float* __restrict__ pT,
                        float* __restrict__ q) {
  int t = blockIdx.x;
  int lane = threadIdx.x;  // 64
  float tr = trct[t * 128 + lane];
  float ct = trct[t * 128 + 64 + lane];
  float ap = fabsf(tr), aq = fabsf(ct);
  float Sp = wave_sum(ap);
  float Sq = wave_sum(aq);
  float denom = 1e-8f + Sp * Sq;
  pT[lane * T_LEN + t] = ap;  // transposed for shuffle-broadcast in scans
  q[t * 64 + lane] = aq / denom;
}

// ---------------- scan phase 1: per-chunk affine summary (A,B) ----------------
// A = prod(st?0:e) = any_start ? 0 : e^64 (closed form); B via recurrence.
__global__ void scan_phase1(const float* __restrict__ pT, const float* __restrict__ q,
                            const unsigned char* __restrict__ st8, const int* __restrict__ st32,
                            const int* __restrict__ modep, const float* __restrict__ a,
                            const float* __restrict__ b, float4* __restrict__ chunkbuf) {
  int chunk = blockIdx.x, r = blockIdx.y, c = threadIdx.x;
  int mode = modep[0];
  int t0 = chunk * CLEN;
  float na = -fabsf(a[r]);
  float rho = __expf(na);
  float bb = b[c];
  float er = rho * __cosf(bb), ei = rho * __sinf(bb);
  float pv = pT[r * T_LEN + t0 + c];             // lane c holds p for step c
  int sv = read_start(st8, st32, mode, t0 + c);  // lane c holds start for step c
  unsigned long long anyb = __ballot(sv != 0);
  float Ar, Ai;
  if (anyb) {
    Ar = 0.f; Ai = 0.f;
  } else {
    float mag = __expf(64.f * na);
    float ang = 64.f * bb;
    Ar = mag * __cosf(ang);
    Ai = mag * __sinf(ang);
  }
  float Br = 0.f, Bi = 0.f;
  const float* qrow = q + (size_t)t0 * 64 + c;
#pragma unroll 8
  for (int i = 0; i < CLEN; ++i) {
    float qt = qrow[i * 64];
    float pt = __shfl(pv, i);
    int st = __shfl(sv, i);
    float pre = pt * qt;
    float cer = st ? 0.f : er;
    float cei = st ? 0.f : ei;
    float nBr = cer * Br - cei * Bi + pre;
    Bi = cer * Bi + cei * Br;
    Br = nBr;
  }
  chunkbuf[((size_t)chunk * 64 + r) * 64 + c] = make_float4(Ar, Ai, Br, Bi);
}

// ---------------- scan phase 2: sequential chunk combine ----------------
__global__ void scan_phase2(const float4* __restrict__ chunkbuf, const float* __restrict__ state,
                            float2* __restrict__ s0buf) {
  int r = blockIdx.x, c = threadIdx.x;
  float Sr = state[r * 64 + c], Si = 0.f;
  for (int k = 0; k < NCHUNK; ++k) {
    s0buf[((size_t)k * 64 + r) * 64 + c] = make_float2(Sr, Si);
    float4 ab = chunkbuf[((size_t)k * 64 + r) * 64 + c];
    float nSr = ab.x * Sr - ab.y * Si + ab.z;
    Si = ab.x * Si + ab.y * Sr + ab.w;
    Sr = nSr;
  }
}

// ---------------- scan phase 3: replay + packed log-polar features ----------------
// scaled dword layout: [t][r*64+c] = (bf16(mag*cos) << 16) | bf16(mag*sin)
// i.e. feature index f = r*128 + 2c + {0=sin,1=cos}; W0 is permuted to match.
__global__ void scan_phase3(const float* __restrict__ pT, const float* __restrict__ q,
                            const unsigned char* __restrict__ st8, const int* __restrict__ st32,
                            const int* __restrict__ modep, const float* __restrict__ a,
                            const float* __restrict__ b, const float2* __restrict__ s0buf,
                            u32* __restrict__ scaled, int c0) {
  int chunk = c0 + blockIdx.x, r = blockIdx.y, c = threadIdx.x;
  int mode = modep[0];
  int t0 = chunk * CLEN;
  float rho = __expf(-fabsf(a[r]));
  float bb = b[c];
  float er = rho * __cosf(bb), ei = rho * __sinf(bb);
  float pv = pT[r * T_LEN + t0 + c];
  int sv = read_start(st8, st32, mode, t0 + c);
  float2 s0 = s0buf[((size_t)chunk * 64 + r) * 64 + c];
  float Sr = s0.x, Si = s0.y;
  int tl0 = (chunk - c0) * CLEN;
  const float* qrow = q + (size_t)t0 * 64 + c;
  u32* drow = scaled + (size_t)tl0 * 4096 + r * 64 + c;
#pragma unroll 4
  for (int i = 0; i < CLEN; ++i) {
    float qt = qrow[i * 64];
    float pt = __shfl(pv, i);
    int st = __shfl(sv, i);
    float pre = pt * qt;
    float cer = st ? 0.f : er;
    float cei = st ? 0.f : ei;
    float nSr = cer * Sr - cei * Si + pre;
    Si = cer * Si + cei * Sr;
    Sr = nSr;
    // sc = log1p(m)/m via hw log2/rsq; rel err ~6e-4 << bf16 quantization
    float m2 = fmaf(Sr, Sr, Si * Si);
    float rsq = rsqrtf(fmaxf(m2, 1e-30f));
    float m = m2 * rsq;
    float sc = __log2f(1.0f + m) * 0.6931471805599453f * rsq;
    u32 pack = ((u32)f2bf_bits(sc * Sr) << 16) | (u32)f2bf_bits(sc * Si);
    drow[(size_t)i * 4096] = pack;
  }
}

// ---------------- LayerNorm + LeakyReLU over summed split-K partials ----------------
__global__ void ln_act(const float* __restrict__ parts, int KS, size_t pstride,
                       const float* __restrict__ bias, const float* __restrict__ gam,
                       const float* __restrict__ bet, u16* __restrict__ zbf,
                       const float* __restrict__ xsrc, float* __restrict__ xdst,
                       u16* __restrict__ xbf_next, float* __restrict__ finout) {
  __shared__ float red[8];
  int t = blockIdx.x, tid = threadIdx.x;
  size_t o = (size_t)t * D_DIM + tid;
  float v0 = bias[tid];
  float v1 = bias[tid + 256];
  for (int ks = 0; ks < KS; ++ks) {
    v0 += parts[(size_t)ks * pstride + o];
    v1 += parts[(size_t)ks * pstride + o + 256];
  }
  float s = wave_sum(v0 + v1);
  if ((tid & 63) == 0) red[tid >> 6] = s;
  __syncthreads();
  float mean = (red[0] + red[1] + red[2] + red[3]) * (1.f / 512.f);
  float d0 = v0 - mean, d1 = v1 - mean;
  float s2 = wave_sum(d0 * d0 + d1 * d1);
  if ((tid & 63) == 0) red[4 + (tid >> 6)] = s2;
  __syncthreads();
  float var = (red[4] + red[5] + red[6] + red[7]) * (1.f / 512.f);
  float rstd = rsqrtf(var + 1e-5f);
  float z0 = d0 * rstd * gam[tid] + bet[tid];
  float z1 = d1 * rstd * gam[tid + 256] + bet[tid + 256];
  z0 = z0 > 0.f ? z0 : 0.01f * z0;
  z1 = z1 > 0.f ? z1 : 0.01f * z1;
  if (zbf) { zbf[o] = f2bf_bits(z0); zbf[o + 256] = f2bf_bits(z1); }
  if (xdst) {
    float x0 = xsrc[o] + z0, x1 = xsrc[o + 256] + z1;
    xdst[o] = x0; xdst[o + 256] = x1;
    if (xbf_next) { xbf_next[o] = f2bf_bits(x0); xbf_next[o + 256] = f2bf_bits(x1); }
  }
  if (finout) { finout[o] = z0; finout[o + 256] = z1; }
}

__global__ void err_signal(float* __restrict__ out, float code) {
  if (threadIdx.x == 0) out[0] = code;
}

// ---------------- host launch ----------------
extern "C" void kernel_launch(void* const* d_in, const int* in_sizes, int n_in, void* d_out,
                              int out_size, void* d_ws, size_t ws_size, hipStream_t stream) {
  const float* x_in = (const float*)d_in[0];
  const float* state = (const float*)d_in[1];
  const unsigned char* start8 = (const unsigned char*)d_in[2];
  const int* start32 = (const int*)d_in[2];
  const float* Wtr = (const float*)d_in[3];
  const float* Wc = (const float*)d_in[4];
  const float* a_in = (const float*)d_in[5];
  const float* b_in = (const float*)d_in[6];
  const float* W0 = (const float*)d_in[7];
  const float* b0 = (const float*)d_in[8];
  const float* g0 = (const float*)d_in[9];
  const float* beta0 = (const float*)d_in[10];
  const float* W1 = (const float*)d_in[11];
  const float* b1 = (const float*)d_in[12];
  const float* g1 = (const float*)d_in[13];
  const float* beta1 = (const float*)d_in[14];
  float* out = (float*)d_out;

  char* w = (char*)d_ws;
  auto alloc = [&](size_t bytes) {
    char* ptr = w;
    w += (bytes + 255) & ~(size_t)255;
    return ptr;
  };
  float* x_ws = (float*)alloc(4ull * T_LEN * D_DIM);            // 8 MB
  u16* xbf = (u16*)alloc(2ull * T_LEN * D_DIM);                 // 4 MB
  u16* wcat = (u16*)alloc(2ull * 128 * D_DIM);                  // 128 KB
  u16* w0bf = (u16*)alloc(2ull * D_DIM * F_DIM);                // 8 MB (per-layer)
  u16* w1bf = (u16*)alloc(2ull * 3 * D_DIM * D_DIM);            // 1.5 MB (all layers)
  float* trct = (float*)alloc(4ull * T_LEN * 128);              // 2 MB
  float* pTbuf = (float*)alloc(4ull * T_LEN * 64);              // 1 MB
  float* qbuf = (float*)alloc(4ull * T_LEN * 64);               // 1 MB
  float4* chunkbuf = (float4*)alloc(16ull * NCHUNK * 64 * 64);  // 4 MB
  float2* s0buf = (float2*)alloc(8ull * NCHUNK * 64 * 64);      // 2 MB
  u16* z0bf = (u16*)alloc(2ull * T_LEN * D_DIM);                // 4 MB
  int* modep = (int*)alloc(256);
  size_t base1 = (size_t)(w - (char*)d_ws);

  if (n_in != 15) {
    err_signal<<<1, 64, 0, stream>>>(out, 9e6f + 1000.f * n_in);
    return;
  }
  const size_t MB = 1ull << 20;
  int KS, nseg;
  if (ws_size >= base1 + 64 * MB + 64 * MB) { KS = 8; nseg = 1; }
  else if (ws_size >= base1 + 32 * MB + 64 * MB) { KS = 4; nseg = 1; }
  else if (ws_size >= base1 + 32 * MB + 32 * MB) { KS = 4; nseg = 2; }
  else if (ws_size >= base1 + 16 * MB + 32 * MB) { KS = 2; nseg = 2; }
  else if (ws_size >= base1 + 16 * MB + 16 * MB) { KS = 2; nseg = 4; }
  else if (ws_size >= base1 + 8 * MB + 16 * MB) { KS = 1; nseg = 4; }
  else {
    err_signal<<<1, 64, 0, stream>>>(out, 9e6f);
    return;
  }
  const int KSw1 = (KS >= 8) ? 4 : ((KS >= 2) ? 2 : 1);
  const int seg_rows = T_LEN / nseg;
  const int seg_chunks = NCHUNK / nseg;
  const size_t pstride = (size_t)T_LEN * D_DIM;
  float* ypart = (float*)alloc(4ull * KS * pstride);
  u16* scaled = (u16*)alloc(2ull * seg_rows * F_DIM);

  detect_start<<<1, 256, 0, stream>>>(start8, modep);
  f2bf<<<(T_LEN * D_DIM) / 256, 256, 0, stream>>>(x_in, xbf, T_LEN * D_DIM);
  f2bf<<<(3 * D_DIM * D_DIM) / 256, 256, 0, stream>>>(W1, w1bf, 3 * D_DIM * D_DIM);

  for (int l = 0; l < 3; ++l) {
    const float* Wtr_l = Wtr + (size_t)l * 64 * D_DIM;
    const float* Wc_l = Wc + (size_t)l * 64 * D_DIM;
    const float* a_l = a_in + l * 64;
    const float* b_l = b_in + l * 64;
    const float* W0_l = W0 + (size_t)l * D_DIM * F_DIM;
    const u16* w1bf_l = w1bf + (size_t)l * D_DIM * D_DIM;
    const float* state_l = state + (size_t)l * 64 * 64;
    const float* xsrc = (l == 0) ? x_in : x_ws;

    k_conv<<<(128 * D_DIM + D_DIM * F_DIM) / 256, 256, 0, stream>>>(Wtr_l, Wc_l, wcat, W0_l,
                                                                    w0bf);
    // trct (4096 x 128) = xbf @ wcat^T
    gemm_bt<64, 64, 2, 2><<<dim3(T_LEN / 64, 2), 256, 0, stream>>>(xbf, wcat, trct, T_LEN, 128,
                                                                   D_DIM);
    prep_pq<<<T_LEN, 64, 0, stream>>>(trct, pTbuf, qbuf);
    scan_phase1<<<dim3(NCHUNK, 64), 64, 0, stream>>>(pTbuf, qbuf, start8, start32, modep, a_l,
                                                     b_l, chunkbuf);
    scan_phase2<<<64, 64, 0, stream>>>(chunkbuf, state_l, s0buf);

    for (int h = 0; h < nseg; ++h) {
      scan_phase3<<<dim3(seg_chunks, 64), 64, 0, stream>>>(pTbuf, qbuf, start8, start32, modep,
                                                           a_l, b_l, s0buf, (u32*)scaled,
                                                           h * seg_chunks);
      gemm128<<<dim3(seg_rows / 128, D_DIM / 128, KS), 256, 0, stream>>>(
          scaled, w0bf, ypart + (size_t)h * seg_rows * D_DIM, pstride, D_DIM, F_DIM);
    }
    ln_act<<<T_LEN, 256, 0, stream>>>(ypart, KS, pstride, b0 + l * D_DIM, g0 + l * D_DIM,
                                      beta0 + l * D_DIM, z0bf, nullptr, nullptr, nullptr,
                                      nullptr);
    gemm128<<<dim3(T_LEN / 128, D_DIM / 128, KSw1), 256, 0, stream>>>(z0bf, w1bf_l, ypart,
                                                                      pstride, D_DIM, D_DIM);
    ln_act<<<T_LEN, 256, 0, stream>>>(ypart, KSw1, pstride, b1 + l * D_DIM, g1 + l * D_DIM,
                                      beta1 + l * D_DIM, nullptr, (l < 2) ? xsrc : nullptr,
                                      (l < 2) ? x_ws : nullptr, (l < 2) ? xbf : nullptr,
                                      (l == 2) ? out : nullptr);
  }
}